// Round 1
// baseline (1903.944 us; speedup 1.0000x reference)
//
#include <hip/hip_runtime.h>
#include <math.h>

#define N_NODES 10000
#define E_EDGES 50000
#define B_BATCH 4
#define NT      40000
#define KS_N    4000
#define ES_E    40000

// ---------- helpers ----------
__device__ __forceinline__ unsigned f2u(float f) {
    unsigned b = __float_as_uint(f);
    return (b & 0x80000000u) ? ~b : (b | 0x80000000u);
}
__device__ __forceinline__ float u2f(unsigned u) {
    unsigned b = (u & 0x80000000u) ? (u & 0x7fffffffu) : ~u;
    return __uint_as_float(b);
}
__device__ __forceinline__ float wave_sum64(float x) {
    for (int off = 32; off > 0; off >>= 1) x += __shfl_down(x, off, 64);
    return x;  // valid on lane 0
}

// ---------- graph build ----------
__global__ void count_deg(const int* __restrict__ ei, unsigned* __restrict__ deg) {
    int j = blockIdx.x * 256 + threadIdx.x;
    if (j < E_EDGES) {
        atomicAdd(&deg[ei[j]], 1u);            // reversed edge dst
        atomicAdd(&deg[ei[E_EDGES + j]], 1u);  // original edge dst
    }
}

__global__ __launch_bounds__(1024) void scan_degrees(const unsigned* __restrict__ deg,
                                                     unsigned* __restrict__ rowptr,
                                                     unsigned* __restrict__ cursor) {
    __shared__ unsigned wsum[16];
    __shared__ unsigned carry;
    int tid = threadIdx.x, lane = tid & 63, w = tid >> 6;
    if (tid == 0) carry = 0;
    __syncthreads();
    for (int base = 0; base < N_NODES; base += 1024) {
        int i = base + tid;
        unsigned v = (i < N_NODES) ? deg[i] : 0u;
        unsigned x = v;
        for (int off = 1; off < 64; off <<= 1) {
            unsigned y = __shfl_up(x, off, 64);
            if (lane >= off) x += y;
        }
        if (lane == 63) wsum[w] = x;
        __syncthreads();
        if (tid < 16) {
            unsigned s = wsum[tid];
            for (int off = 1; off < 16; off <<= 1) {
                unsigned y = __shfl_up(s, off, 64);
                if (tid >= off) s += y;
            }
            wsum[tid] = s;
        }
        __syncthreads();
        unsigned woff = (w > 0) ? wsum[w - 1] : 0u;
        unsigned excl = carry + woff + x - v;
        if (i < N_NODES) { rowptr[i] = excl; cursor[i] = excl; }
        __syncthreads();
        if (tid == 0) carry += wsum[15];
        __syncthreads();
    }
    if (tid == 0) rowptr[N_NODES] = carry;
}

__global__ void scatter_edges(const int* __restrict__ ei, const int* __restrict__ ea,
                              unsigned* __restrict__ cursor, unsigned* __restrict__ inedge) {
    int j = blockIdx.x * 256 + threadIdx.x;
    if (j < E_EDGES) {
        unsigned s = (unsigned)ei[j];
        unsigned d = (unsigned)ei[E_EDGES + j];
        unsigned a = (unsigned)ea[j];
        unsigned p1 = atomicAdd(&cursor[d], 1u);   // original edge: in-edge of d from s
        inedge[p1] = s | (a << 16);
        unsigned p2 = atomicAdd(&cursor[s], 1u);   // reversed edge: in-edge of s from d
        inedge[p2] = d | (a << 16);
    }
}

__global__ void pna_kernel(const unsigned* __restrict__ deg, float* __restrict__ scalars) {
    int n = blockIdx.x * 256 + threadIdx.x;
    float v = (n < N_NODES) ? logf((float)deg[n] + 1.0f) : 0.0f;
    float s = wave_sum64(v);
    if ((threadIdx.x & 63) == 0) atomicAdd(&scalars[2], s);
}

__global__ void finalize_kernel(float* scalars) {
    scalars[3] = scalars[2] / (float)N_NODES;  // pna_mean (mean over Nt == mean over N)
}

// ---------- init ----------
__global__ void init_hidden(const float* __restrict__ text, float* __restrict__ hidden) {
    int i = blockIdx.x * 256 + threadIdx.x;
    if (i < NT * 64) {
        int v = i >> 6;
        hidden[i] = (v < N_NODES) ? text[i] : 0.0f;
    }
}

__device__ float wave_score_g(float hid, float rel, const float* Wlin, const float* blin,
                              const float* W1, const float* b1, const float* W2, float b2v,
                              int lane) {
    float heur = blin[lane];
    for (int i = 0; i < 64; ++i) heur += __shfl(hid, i, 64) * Wlin[i * 64 + lane];
    for (int i = 0; i < 64; ++i) heur += __shfl(rel, i, 64) * Wlin[(64 + i) * 64 + lane];
    float x = hid * heur;
    float a0 = b1[lane], a1 = b1[64 + lane];
    for (int i = 0; i < 64; ++i) {
        float xv = __shfl(x, i, 64);
        a0 += xv * W1[i * 128 + lane];
        a1 += xv * W1[i * 128 + 64 + lane];
    }
    a0 = fmaxf(a0, 0.0f); a1 = fmaxf(a1, 0.0f);
    float part = a0 * W2[lane] + a1 * W2[64 + lane];
    part = wave_sum64(part);
    part = __shfl(part, 0, 64);
    return part + b2v;
}

__global__ void init_heads(const int* __restrict__ h_index, const int* __restrict__ r_index,
                           const float* __restrict__ hidden_states,
                           const float* __restrict__ rel_table,
                           const float* __restrict__ W_lin, const float* __restrict__ b_lin,
                           const float* __restrict__ W1, const float* __restrict__ b1,
                           const float* __restrict__ W2, const float* __restrict__ b2,
                           float* __restrict__ hidden, float* __restrict__ score,
                           float* __restrict__ qh) {
    __shared__ float q0[64];
    int tid = threadIdx.x, w = tid >> 6, lane = tid & 63;
    int b = w;  // 4 waves, one per batch element
    int h0 = h_index[b * 16] + b * N_NODES;
    float hs  = hidden_states[b * 64 + lane];
    float rel = rel_table[r_index[b * 16] * 64 + lane];
    hidden[h0 * 64 + lane] = hs;
    if (b == 0) q0[lane] = rel;
    float s = wave_score_g(hs, rel, W_lin, b_lin, W1, b1, W2, b2[0], lane);
    if (lane == 0) score[h0] = s;
    __syncthreads();
    if (w == 0) {  // qh[t] = sum_i q0[i]*W_lin[64+i][t] + b_lin[t]
        float acc = b_lin[lane];
        for (int i = 0; i < 64; ++i) acc += q0[i] * W_lin[(64 + i) * 64 + lane];
        qh[lane] = acc;
    }
}

// ---------- selection (exact k-th largest, radix over monotone u32 keys) ----------
__global__ void select_kth(const float* __restrict__ vals, float* __restrict__ scalars) {
    __shared__ unsigned hist[256];
    __shared__ unsigned sh_prefix, sh_r;
    int tid = threadIdx.x;
    if (tid == 0) { sh_prefix = 0; sh_r = NT - KS_N; }  // ascending rank
    __syncthreads();
    for (int pass = 0; pass < 4; ++pass) {
        hist[tid] = 0;
        __syncthreads();
        unsigned pref = sh_prefix;
        int shift = 24 - pass * 8;
        for (int i = tid; i < NT; i += 256) {
            unsigned key = f2u(vals[i]);
            if (pass == 0 || (key >> (shift + 8)) == pref)
                atomicAdd(&hist[(key >> shift) & 255u], 1u);
        }
        __syncthreads();
        if (tid == 0) {
            unsigned r = sh_r, cum = 0; int d = 0;
            for (; d < 256; ++d) { unsigned h = hist[d]; if (cum + h > r) break; cum += h; }
            sh_r = r - cum;
            sh_prefix = (pref << 8) | (unsigned)d;
        }
        __syncthreads();
    }
    if (tid == 0) scalars[0] = u2f(sh_prefix);  // thr
}

__global__ void select_weighted(const float* __restrict__ score, const unsigned* __restrict__ degb,
                                float* __restrict__ scalars) {
    __shared__ unsigned hist[256];
    __shared__ unsigned sh_prefix, sh_r, sh_T;
    int tid = threadIdx.x;
    float thr = scalars[0];
    // total weight T
    unsigned tp = 0;
    for (int v = tid; v < NT; v += 256)
        if (score[v] >= thr) tp += degb[v % N_NODES];
    hist[tid] = tp;
    __syncthreads();
    for (int s = 128; s > 0; s >>= 1) { if (tid < s) hist[tid] += hist[tid + s]; __syncthreads(); }
    if (tid == 0) sh_T = hist[0];
    __syncthreads();
    unsigned T = sh_T;
    if (T < (unsigned)ES_E) {  // thr_e = -inf  =>  effective threshold = thr
        if (tid == 0) scalars[1] = thr;
        return;
    }
    if (tid == 0) { sh_prefix = 0; sh_r = T - ES_E; }
    __syncthreads();
    for (int pass = 0; pass < 4; ++pass) {
        hist[tid] = 0;
        __syncthreads();
        unsigned pref = sh_prefix;
        int shift = 24 - pass * 8;
        for (int v = tid; v < NT; v += 256) {
            float sc = score[v];
            if (sc >= thr) {
                unsigned wgt = degb[v % N_NODES];
                if (wgt) {
                    unsigned key = f2u(sc);
                    if (pass == 0 || (key >> (shift + 8)) == pref)
                        atomicAdd(&hist[(key >> shift) & 255u], wgt);
                }
            }
        }
        __syncthreads();
        if (tid == 0) {
            unsigned r = sh_r, cum = 0; int d = 0;
            for (; d < 256; ++d) { unsigned h = hist[d]; if (cum + h > r) break; cum += h; }
            sh_r = r - cum;
            sh_prefix = (pref << 8) | (unsigned)d;
        }
        __syncthreads();
    }
    if (tid == 0) scalars[1] = u2f(sh_prefix);  // THR (= thr_e, >= thr)
}

// ---------- aggregation + PNA feat + 768x64 update GEMM ----------
__global__ __launch_bounds__(512) void aggregate(
    const float* __restrict__ score, const float* __restrict__ hidden,
    const unsigned* __restrict__ rowptr, const unsigned* __restrict__ inedge,
    const unsigned* __restrict__ degb, const float* __restrict__ rel_w,
    const float* __restrict__ conv_W, const float* __restrict__ conv_b,
    const float* __restrict__ scalars, float* __restrict__ upd,
    unsigned* __restrict__ flags, int layer) {
    __shared__ float wlds[12288];  // 3 x 64 x 64 (48 KB)
    int tid = threadIdx.x, w = tid >> 6, lane = tid & 63;
    int v = blockIdx.x * 8 + w;               // grid sized exactly NT/8
    int b = v / N_NODES;
    int n = v - b * N_NODES;
    float THR = scalars[1];
    float pna = scalars[3];
    unsigned r0 = rowptr[n], r1 = rowptr[n + 1];
    int boff = b * N_NODES;
    float sum = 0.0f, sq = 0.0f;
    float mx = -INFINITY, mn = INFINITY;
    int cnt = 0;
    for (unsigned e = r0; e < r1; ++e) {
        unsigned pk = inedge[e];
        int src = (int)(pk & 0xffffu) + boff;
        float sc = score[src];
        if (sc >= THR) {
            int attr = (int)(pk >> 16);
            float sig = 1.0f / (1.0f + expf(-sc));
            float m = sig * hidden[src * 64 + lane] * rel_w[(layer * 400 + attr) * 64 + lane];
            sum += m; sq += m * m;
            mx = fmaxf(mx, m); mn = fminf(mn, m);
            ++cnt;
        }
    }
    float denom = cnt > 0 ? (float)cnt : 1.0f;
    float mean = sum / denom;
    float var  = fmaxf(sq / denom - mean * mean, 0.0f);
    float sd   = sqrtf(var + 1e-6f);
    float fmx  = cnt > 0 ? mx : 0.0f;
    float fmn  = cnt > 0 ? mn : 0.0f;
    float degf = (float)cnt;
    float sl   = logf(degf + 1.0f);
    float amp  = sl / pna;
    float att  = pna / (sl + 1e-6f);

    float acc1 = 0.0f, acc2 = 0.0f, acc3 = 0.0f;
    const float* Wl = conv_W + (size_t)layer * 768 * 64;
    for (int q = 0; q < 4; ++q) {
        __syncthreads();
        for (int i = tid; i < 12288; i += 512) {
            int blk = i >> 12, rem = i & 4095;
            wlds[i] = Wl[(blk * 256 + q * 64) * 64 + rem];
        }
        __syncthreads();
        float fq = (q == 0) ? mean : (q == 1) ? fmx : (q == 2) ? fmn : sd;
        #pragma unroll 4
        for (int i = 0; i < 64; ++i) {
            float fv = __shfl(fq, i, 64);
            acc1 += fv * wlds[i * 64 + lane];
            acc2 += fv * wlds[4096 + i * 64 + lane];
            acc3 += fv * wlds[8192 + i * 64 + lane];
        }
    }
    float outv = fmaxf(acc1 + amp * acc2 + att * acc3 + conv_b[layer * 64 + lane], 0.0f);
    upd[(size_t)v * 64 + lane] = outv;
    if (lane == 0)
        flags[v] = (score[v] >= THR && degb[n] > 0) ? 1u : 0u;
}

// ---------- apply update + score MLP ----------
__global__ __launch_bounds__(256) void apply_and_score(
    float* __restrict__ hidden, const float* __restrict__ upd,
    float* __restrict__ score, const unsigned* __restrict__ flags,
    const float* __restrict__ W_lin, const float* __restrict__ qh,
    const float* __restrict__ W1, const float* __restrict__ b1,
    const float* __restrict__ W2, const float* __restrict__ b2) {
    __shared__ float sWl[4096];   // W_lin rows 0..63
    __shared__ float sW1[8192];
    __shared__ float sW2[128];
    __shared__ float sB1[128];
    __shared__ float sQh[64];
    int tid = threadIdx.x;
    for (int i = tid; i < 4096; i += 256) sWl[i] = W_lin[i];
    for (int i = tid; i < 8192; i += 256) sW1[i] = W1[i];
    if (tid < 128) { sW2[tid] = W2[tid]; sB1[tid] = b1[tid]; }
    if (tid < 64) sQh[tid] = qh[tid];
    __syncthreads();
    float b2v = b2[0];
    int w = tid >> 6, lane = tid & 63;
    for (int v = blockIdx.x * 4 + w; v < NT; v += gridDim.x * 4) {
        if (!flags[v]) continue;
        float h = hidden[(size_t)v * 64 + lane] + upd[(size_t)v * 64 + lane];
        hidden[(size_t)v * 64 + lane] = h;
        float heur = sQh[lane];
        #pragma unroll 4
        for (int i = 0; i < 64; ++i) heur += __shfl(h, i, 64) * sWl[i * 64 + lane];
        float x = h * heur;
        float a0 = sB1[lane], a1 = sB1[64 + lane];
        #pragma unroll 4
        for (int i = 0; i < 64; ++i) {
            float xv = __shfl(x, i, 64);
            a0 += xv * sW1[i * 128 + lane];
            a1 += xv * sW1[i * 128 + 64 + lane];
        }
        a0 = fmaxf(a0, 0.0f); a1 = fmaxf(a1, 0.0f);
        float part = a0 * sW2[lane] + a1 * sW2[64 + lane];
        part = wave_sum64(part);
        if (lane == 0) score[v] = part + b2v;
    }
}

// ---------- output gather ----------
__global__ void gather_out(const float* __restrict__ score, const int* __restrict__ t_index,
                           float* __restrict__ out) {
    int i = threadIdx.x;  // 64 threads
    int b = i >> 4;
    out[i] = score[t_index[i] + b * N_NODES];
}

// ---------- launcher ----------
extern "C" void kernel_launch(void* const* d_in, const int* in_sizes, int n_in,
                              void* d_out, int out_size, void* d_ws, size_t ws_size,
                              hipStream_t stream) {
    const int*   h_index       = (const int*)d_in[0];
    const int*   r_index       = (const int*)d_in[1];
    const int*   t_index       = (const int*)d_in[2];
    const float* hidden_states = (const float*)d_in[3];
    const int*   edge_index    = (const int*)d_in[5];
    const int*   edge_attr     = (const int*)d_in[6];
    const float* text          = (const float*)d_in[7];
    const float* rel_table     = (const float*)d_in[9];
    const float* W_lin         = (const float*)d_in[10];
    const float* b_lin         = (const float*)d_in[11];
    const float* W1            = (const float*)d_in[12];
    const float* b1            = (const float*)d_in[13];
    const float* W2            = (const float*)d_in[14];
    const float* b2            = (const float*)d_in[15];
    const float* rel_w         = (const float*)d_in[16];
    const float* conv_W        = (const float*)d_in[17];
    const float* conv_b        = (const float*)d_in[18];

    char* ws = (char*)d_ws;
    size_t off = 0;
    auto carve = [&](size_t bytes) -> char* {
        char* p = ws + off;
        off = (off + bytes + 255) & ~(size_t)255;
        return p;
    };
    float*    scalars = (float*)carve(256);                 // [0]=thr [1]=THR [2]=pna_sum [3]=pna_mean
    float*    qh      = (float*)carve(256);
    float*    score   = (float*)carve((size_t)NT * 4);
    float*    hidden  = (float*)carve((size_t)NT * 64 * 4);
    float*    upd     = (float*)carve((size_t)NT * 64 * 4);
    unsigned* flags   = (unsigned*)carve((size_t)NT * 4);
    unsigned* degb    = (unsigned*)carve((size_t)N_NODES * 4);
    unsigned* rowptr  = (unsigned*)carve((size_t)(N_NODES + 1) * 4);
    unsigned* cursor  = (unsigned*)carve((size_t)N_NODES * 4);
    unsigned* inedge  = (unsigned*)carve((size_t)2 * E_EDGES * 4);
    if (off > ws_size) return;  // not enough scratch; cannot proceed

    hipMemsetAsync(scalars, 0, 256, stream);
    hipMemsetAsync(score, 0, (size_t)NT * 4, stream);
    hipMemsetAsync(degb, 0, (size_t)N_NODES * 4, stream);

    count_deg<<<(E_EDGES + 255) / 256, 256, 0, stream>>>(edge_index, degb);
    scan_degrees<<<1, 1024, 0, stream>>>(degb, rowptr, cursor);
    scatter_edges<<<(E_EDGES + 255) / 256, 256, 0, stream>>>(edge_index, edge_attr, cursor, inedge);
    pna_kernel<<<(N_NODES + 255) / 256, 256, 0, stream>>>(degb, scalars);
    finalize_kernel<<<1, 1, 0, stream>>>(scalars);
    init_hidden<<<(NT * 64 + 255) / 256, 256, 0, stream>>>(text, hidden);
    init_heads<<<1, 256, 0, stream>>>(h_index, r_index, hidden_states, rel_table,
                                      W_lin, b_lin, W1, b1, W2, b2, hidden, score, qh);

    for (int l = 0; l < 3; ++l) {
        select_kth<<<1, 256, 0, stream>>>(score, scalars);
        select_weighted<<<1, 256, 0, stream>>>(score, degb, scalars);
        aggregate<<<NT / 8, 512, 0, stream>>>(score, hidden, rowptr, inedge, degb,
                                              rel_w, conv_W, conv_b, scalars, upd, flags, l);
        apply_and_score<<<2500, 256, 0, stream>>>(hidden, upd, score, flags,
                                                  W_lin, qh, W1, b1, W2, b2);
    }
    gather_out<<<1, 64, 0, stream>>>(score, t_index, (float*)d_out);
}

// Round 2
// 835.225 us; speedup vs baseline: 2.2796x; 2.2796x over previous
//
#include <hip/hip_runtime.h>
#include <math.h>

#define N_NODES 10000
#define E_EDGES 50000
#define NT      40000
#define KS_N    4000
#define ES_E    40000
#define WTOT    400000u   // sum of in-degrees over batched graph (2*E*B), constant

// ---------- helpers ----------
__device__ __forceinline__ unsigned f2u(float f) {
    unsigned b = __float_as_uint(f);
    return (b & 0x80000000u) ? ~b : (b | 0x80000000u);
}
__device__ __forceinline__ float u2f(unsigned u) {
    unsigned b = (u & 0x80000000u) ? (u & 0x7fffffffu) : ~u;
    return __uint_as_float(b);
}
__device__ __forceinline__ float wave_sum64(float x) {
    for (int off = 32; off > 0; off >>= 1) x += __shfl_down(x, off, 64);
    return x;  // valid on lane 0
}

// ---------- graph build ----------
__global__ void count_deg(const int* __restrict__ ei, unsigned* __restrict__ deg) {
    int j = blockIdx.x * 256 + threadIdx.x;
    if (j < E_EDGES) {
        atomicAdd(&deg[ei[j]], 1u);
        atomicAdd(&deg[ei[E_EDGES + j]], 1u);
    }
}

__global__ __launch_bounds__(1024) void scan_degrees(const unsigned* __restrict__ deg,
                                                     unsigned* __restrict__ rowptr,
                                                     unsigned* __restrict__ cursor) {
    __shared__ unsigned wsum[16];
    __shared__ unsigned carry;
    int tid = threadIdx.x, lane = tid & 63, w = tid >> 6;
    if (tid == 0) carry = 0;
    __syncthreads();
    for (int base = 0; base < N_NODES; base += 1024) {
        int i = base + tid;
        unsigned v = (i < N_NODES) ? deg[i] : 0u;
        unsigned x = v;
        for (int off = 1; off < 64; off <<= 1) {
            unsigned y = __shfl_up(x, off, 64);
            if (lane >= off) x += y;
        }
        if (lane == 63) wsum[w] = x;
        __syncthreads();
        if (tid < 16) {
            unsigned s = wsum[tid];
            for (int off = 1; off < 16; off <<= 1) {
                unsigned y = __shfl_up(s, off, 64);
                if (tid >= off) s += y;
            }
            wsum[tid] = s;
        }
        __syncthreads();
        unsigned woff = (w > 0) ? wsum[w - 1] : 0u;
        unsigned excl = carry + woff + x - v;
        if (i < N_NODES) { rowptr[i] = excl; cursor[i] = excl; }
        __syncthreads();
        if (tid == 0) carry += wsum[15];
        __syncthreads();
    }
    if (tid == 0) rowptr[N_NODES] = carry;
}

__global__ void scatter_edges(const int* __restrict__ ei, const int* __restrict__ ea,
                              unsigned* __restrict__ cursor, unsigned* __restrict__ inedge) {
    int j = blockIdx.x * 256 + threadIdx.x;
    if (j < E_EDGES) {
        unsigned s = (unsigned)ei[j];
        unsigned d = (unsigned)ei[E_EDGES + j];
        unsigned a = (unsigned)ea[j];
        unsigned p1 = atomicAdd(&cursor[d], 1u);
        inedge[p1] = s | (a << 16);
        unsigned p2 = atomicAdd(&cursor[s], 1u);
        inedge[p2] = d | (a << 16);
    }
}

__global__ void tile_degb(const unsigned* __restrict__ degb, unsigned* __restrict__ degbt) {
    int v = blockIdx.x * 256 + threadIdx.x;
    if (v < NT) degbt[v] = degb[v % N_NODES];
}

// deterministic single-block pna mean
__global__ __launch_bounds__(1024) void pna_kernel(const unsigned* __restrict__ degb,
                                                   float* __restrict__ scalars) {
    __shared__ float ws[16];
    int tid = threadIdx.x;
    float s = 0.0f;
    for (int i = tid; i < N_NODES; i += 1024) s += logf((float)degb[i] + 1.0f);
    for (int off = 32; off > 0; off >>= 1) s += __shfl_down(s, off, 64);
    if ((tid & 63) == 0) ws[tid >> 6] = s;
    __syncthreads();
    if (tid == 0) {
        float t = 0.0f;
        for (int i = 0; i < 16; ++i) t += ws[i];
        scalars[3] = t / (float)N_NODES;
    }
}

// ---------- init ----------
__global__ void init_hidden(const float* __restrict__ text, float* __restrict__ hidden) {
    int i = blockIdx.x * 256 + threadIdx.x;
    if (i < NT * 64) {
        int v = i >> 6;
        hidden[i] = (v < N_NODES) ? text[i] : 0.0f;
    }
}

__device__ float wave_score_g(float hid, float rel, const float* Wlin, const float* blin,
                              const float* W1, const float* b1, const float* W2, float b2v,
                              int lane) {
    float heur = blin[lane];
    for (int i = 0; i < 64; ++i) heur += __shfl(hid, i, 64) * Wlin[i * 64 + lane];
    for (int i = 0; i < 64; ++i) heur += __shfl(rel, i, 64) * Wlin[(64 + i) * 64 + lane];
    float x = hid * heur;
    float a0 = b1[lane], a1 = b1[64 + lane];
    for (int i = 0; i < 64; ++i) {
        float xv = __shfl(x, i, 64);
        a0 += xv * W1[i * 128 + lane];
        a1 += xv * W1[i * 128 + 64 + lane];
    }
    a0 = fmaxf(a0, 0.0f); a1 = fmaxf(a1, 0.0f);
    float part = a0 * W2[lane] + a1 * W2[64 + lane];
    part = wave_sum64(part);
    part = __shfl(part, 0, 64);
    return part + b2v;
}

__global__ void init_heads(const int* __restrict__ h_index, const int* __restrict__ r_index,
                           const float* __restrict__ hidden_states,
                           const float* __restrict__ rel_table,
                           const float* __restrict__ W_lin, const float* __restrict__ b_lin,
                           const float* __restrict__ W1, const float* __restrict__ b1,
                           const float* __restrict__ W2, const float* __restrict__ b2,
                           float* __restrict__ hidden, float* __restrict__ score,
                           float* __restrict__ qh) {
    __shared__ float q0[64];
    int tid = threadIdx.x, w = tid >> 6, lane = tid & 63;
    int b = w;  // 4 waves, one per batch element
    int h0 = h_index[b * 16] + b * N_NODES;
    float hs  = hidden_states[b * 64 + lane];
    float rel = rel_table[r_index[b * 16] * 64 + lane];
    hidden[h0 * 64 + lane] = hs;
    if (b == 0) q0[lane] = rel;
    float s = wave_score_g(hs, rel, W_lin, b_lin, W1, b1, W2, b2[0], lane);
    if (lane == 0) score[h0] = s;
    __syncthreads();
    if (w == 0) {  // qh[t] = sum_i q0[i]*W_lin[64+i][t] + b_lin[t]
        float acc = b_lin[lane];
        for (int i = 0; i < 64; ++i) acc += q0[i] * W_lin[(64 + i) * 64 + lane];
        qh[lane] = acc;
    }
}

// ---------- fused dual radix select (node count + degree-weighted) ----------
__global__ void hist_pass(const float* __restrict__ score, const unsigned* __restrict__ degbt,
                          unsigned* __restrict__ ghn, unsigned* __restrict__ ghw,
                          const unsigned* __restrict__ state, int pass) {
    __shared__ unsigned lh[512];
    int tid = threadIdx.x;
    lh[tid] = 0; lh[256 + tid] = 0;
    __syncthreads();
    unsigned pn = state[0], pw = state[2];
    int shift = 24 - pass * 8;
    for (int v = blockIdx.x * 256 + tid; v < NT; v += gridDim.x * 256) {
        unsigned key = f2u(score[v]);
        unsigned wg = degbt[v];
        unsigned dig = (key >> shift) & 255u;
        if (pass == 0) {
            atomicAdd(&lh[dig], 1u);
            if (wg) atomicAdd(&lh[256 + dig], wg);
        } else {
            unsigned hi = key >> (shift + 8);
            if (hi == pn) atomicAdd(&lh[dig], 1u);
            if (wg && hi == pw) atomicAdd(&lh[256 + dig], wg);
        }
    }
    __syncthreads();
    if (lh[tid]) atomicAdd(&ghn[tid], lh[tid]);
    if (lh[256 + tid]) atomicAdd(&ghw[tid], lh[256 + tid]);
}

__global__ void pick_pass(unsigned* __restrict__ ghn, unsigned* __restrict__ ghw,
                          unsigned* __restrict__ state, float* __restrict__ scalars,
                          unsigned* __restrict__ countp, int pass) {
    __shared__ unsigned hn[256], hw[256];
    int tid = threadIdx.x;
    hn[tid] = ghn[tid]; hw[tid] = ghw[tid];
    ghn[tid] = 0; ghw[tid] = 0;   // zero for next pass / next layer
    __syncthreads();
    if (tid == 0) {
        unsigned pn, rn, pw, rw;
        if (pass == 0) { pn = 0; rn = NT - KS_N; pw = 0; rw = WTOT - ES_E; }
        else { pn = state[0]; rn = state[1]; pw = state[2]; rw = state[3]; }
        unsigned cum = 0; int d = 0;
        for (; d < 256; ++d) { unsigned h = hn[d]; if (cum + h > rn) break; cum += h; }
        pn = (pn << 8) | (unsigned)d; rn -= cum;
        cum = 0; int dw = 0;
        for (; dw < 256; ++dw) { unsigned h = hw[dw]; if (cum + h > rw) break; cum += h; }
        pw = (pw << 8) | (unsigned)dw; rw -= cum;
        state[0] = pn; state[1] = rn; state[2] = pw; state[3] = rw;
        if (pass == 3) {
            float thr = u2f(pn), thre = u2f(pw);
            scalars[0] = thr;
            scalars[1] = fmaxf(thr, thre);  // THR (== reference's effective edge threshold)
            *countp = 0;
        }
    }
}

__global__ void compact(const float* __restrict__ score, const unsigned* __restrict__ degbt,
                        const float* __restrict__ scalars, unsigned* __restrict__ countp,
                        int* __restrict__ list) {
    int v = blockIdx.x * 256 + threadIdx.x;
    if (v >= NT) return;
    if (score[v] >= scalars[1] && degbt[v] > 0) {
        unsigned p = atomicAdd(countp, 1u);
        list[p] = v;
    }
}

// ---------- fused aggregation + PNA feat + tiled 32x192x256 update GEMM ----------
__global__ __launch_bounds__(256) void node_update(
    const float* __restrict__ score, const float* __restrict__ hidden,
    const unsigned* __restrict__ rowptr, const unsigned* __restrict__ inedge,
    const float* __restrict__ rel_w, const float* __restrict__ conv_W,
    const float* __restrict__ conv_b, const float* __restrict__ scalars,
    const unsigned* __restrict__ countp, const int* __restrict__ list,
    float* __restrict__ updc, int layer) {
    __shared__ float fT[32 * 264];    // feat[m][k], pad 264 to dodge bank aliasing
    __shared__ float sB[32 * 196];    // W chunk [k][3*64], pad 196
    __shared__ float sAmp[32], sAtt[32];
    int count = (int)*countp;
    int m0 = blockIdx.x * 32;
    if (m0 >= count) return;
    int tid = threadIdx.x, w = tid >> 6, lane = tid & 63;
    float THR = scalars[1], pna = scalars[3];
    const float* rw = rel_w + (size_t)layer * 400 * 64;
    // ---- edge aggregation: 8 nodes per wave ----
    for (int t = 0; t < 8; ++t) {
        int m = w * 8 + t;
        int idx = m0 + m;
        if (idx < count) {
            int v = list[idx];
            int b = v / N_NODES;
            int boff = b * N_NODES;
            int n = v - boff;
            unsigned r0 = rowptr[n], r1 = rowptr[n + 1];
            float sum = 0.f, sq = 0.f, mx = -INFINITY, mn = INFINITY;
            int cnt = 0;
            for (unsigned e = r0; e < r1; ++e) {
                unsigned pk = inedge[e];
                int src = (int)(pk & 0xffffu) + boff;
                float sc = score[src];
                if (sc >= THR) {
                    float sig = 1.0f / (1.0f + expf(-sc));
                    float mval = sig * hidden[(size_t)src * 64 + lane] * rw[(pk >> 16) * 64 + lane];
                    sum += mval; sq += mval * mval;
                    mx = fmaxf(mx, mval); mn = fminf(mn, mval);
                    ++cnt;
                }
            }
            float denom = cnt > 0 ? (float)cnt : 1.0f;
            float mean = sum / denom;
            float sd = sqrtf(fmaxf(sq / denom - mean * mean, 0.0f) + 1e-6f);
            fT[m * 264 + lane]       = mean;
            fT[m * 264 + 64 + lane]  = cnt > 0 ? mx : 0.0f;
            fT[m * 264 + 128 + lane] = cnt > 0 ? mn : 0.0f;
            fT[m * 264 + 192 + lane] = sd;
            if (lane == 0) {
                float sl = logf((float)cnt + 1.0f);
                sAmp[m] = sl / pna;
                sAtt[m] = pna / (sl + 1e-6f);
            }
        }
    }
    // ---- tiled GEMM: c{0,1,2}[2 rows][4 cols] per thread ----
    int mg = tid >> 4, ng = tid & 15;
    int j0 = ng * 4;
    float c0[2][4] = {{0}}, c1[2][4] = {{0}}, c2[2][4] = {{0}};
    const float* Wl = conv_W + (size_t)layer * 768 * 64;
    for (int k0 = 0; k0 < 256; k0 += 32) {
        __syncthreads();
        for (int it = 0; it < 6; ++it) {
            int fi = it * 256 + tid;
            int rr = fi >> 4, q = fi & 15;
            int bblk = rr >> 5, kk = rr & 31;
            const float4 vb = *(const float4*)(Wl + ((size_t)(bblk * 256 + k0 + kk) << 6) + q * 4);
            float* d = &sB[kk * 196 + bblk * 64 + q * 4];
            d[0] = vb.x; d[1] = vb.y; d[2] = vb.z; d[3] = vb.w;
        }
        __syncthreads();
        for (int kk = 0; kk < 32; ++kk) {
            int k = k0 + kk;
            float a0 = fT[(mg * 2) * 264 + k];
            float a1 = fT[(mg * 2 + 1) * 264 + k];
            const float4 b0 = *(const float4*)&sB[kk * 196 + j0];
            const float4 b1v = *(const float4*)&sB[kk * 196 + 64 + j0];
            const float4 b2v = *(const float4*)&sB[kk * 196 + 128 + j0];
            c0[0][0] += a0 * b0.x;  c0[0][1] += a0 * b0.y;  c0[0][2] += a0 * b0.z;  c0[0][3] += a0 * b0.w;
            c0[1][0] += a1 * b0.x;  c0[1][1] += a1 * b0.y;  c0[1][2] += a1 * b0.z;  c0[1][3] += a1 * b0.w;
            c1[0][0] += a0 * b1v.x; c1[0][1] += a0 * b1v.y; c1[0][2] += a0 * b1v.z; c1[0][3] += a0 * b1v.w;
            c1[1][0] += a1 * b1v.x; c1[1][1] += a1 * b1v.y; c1[1][2] += a1 * b1v.z; c1[1][3] += a1 * b1v.w;
            c2[0][0] += a0 * b2v.x; c2[0][1] += a0 * b2v.y; c2[0][2] += a0 * b2v.z; c2[0][3] += a0 * b2v.w;
            c2[1][0] += a1 * b2v.x; c2[1][1] += a1 * b2v.y; c2[1][2] += a1 * b2v.z; c2[1][3] += a1 * b2v.w;
        }
    }
    const float4 bias = *(const float4*)(conv_b + layer * 64 + j0);
    #pragma unroll
    for (int mi = 0; mi < 2; ++mi) {
        int m = mg * 2 + mi;
        int row = m0 + m;
        if (row < count) {
            float amp = sAmp[m], att = sAtt[m];
            float4 o;
            o.x = fmaxf(c0[mi][0] + amp * c1[mi][0] + att * c2[mi][0] + bias.x, 0.0f);
            o.y = fmaxf(c0[mi][1] + amp * c1[mi][1] + att * c2[mi][1] + bias.y, 0.0f);
            o.z = fmaxf(c0[mi][2] + amp * c1[mi][2] + att * c2[mi][2] + bias.z, 0.0f);
            o.w = fmaxf(c0[mi][3] + amp * c1[mi][3] + att * c2[mi][3] + bias.w, 0.0f);
            *(float4*)(updc + ((size_t)row << 6) + j0) = o;
        }
    }
}

// ---------- apply update + score MLP over compacted list ----------
__global__ __launch_bounds__(256) void apply_score(
    float* __restrict__ hidden, const float* __restrict__ updc,
    float* __restrict__ score, const unsigned* __restrict__ countp,
    const int* __restrict__ list,
    const float* __restrict__ W_lin, const float* __restrict__ qh,
    const float* __restrict__ W1, const float* __restrict__ b1,
    const float* __restrict__ W2, const float* __restrict__ b2) {
    __shared__ float sWl[4096];
    __shared__ float sW1[8192];
    __shared__ float sW2[128];
    __shared__ float sB1[128];
    __shared__ float sQh[64];
    int count = (int)*countp;
    if ((int)blockIdx.x * 4 >= count) return;
    int tid = threadIdx.x;
    for (int i = tid; i < 4096; i += 256) sWl[i] = W_lin[i];
    for (int i = tid; i < 8192; i += 256) sW1[i] = W1[i];
    if (tid < 128) { sW2[tid] = W2[tid]; sB1[tid] = b1[tid]; }
    if (tid < 64) sQh[tid] = qh[tid];
    __syncthreads();
    float b2v = b2[0];
    int w = tid >> 6, lane = tid & 63;
    for (int idx = blockIdx.x * 4 + w; idx < count; idx += gridDim.x * 4) {
        int v = list[idx];
        float h = hidden[(size_t)v * 64 + lane] + updc[(size_t)idx * 64 + lane];
        hidden[(size_t)v * 64 + lane] = h;
        float heur = sQh[lane];
        #pragma unroll 4
        for (int i = 0; i < 64; ++i) heur += __shfl(h, i, 64) * sWl[i * 64 + lane];
        float x = h * heur;
        float a0 = sB1[lane], a1 = sB1[64 + lane];
        #pragma unroll 4
        for (int i = 0; i < 64; ++i) {
            float xv = __shfl(x, i, 64);
            a0 += xv * sW1[i * 128 + lane];
            a1 += xv * sW1[i * 128 + 64 + lane];
        }
        a0 = fmaxf(a0, 0.0f); a1 = fmaxf(a1, 0.0f);
        float part = a0 * sW2[lane] + a1 * sW2[64 + lane];
        part = wave_sum64(part);
        if (lane == 0) score[v] = part + b2v;
    }
}

// ---------- output gather ----------
__global__ void gather_out(const float* __restrict__ score, const int* __restrict__ t_index,
                           float* __restrict__ out) {
    int i = threadIdx.x;  // 64 threads
    int b = i >> 4;
    out[i] = score[t_index[i] + b * N_NODES];
}

// ---------- launcher ----------
extern "C" void kernel_launch(void* const* d_in, const int* in_sizes, int n_in,
                              void* d_out, int out_size, void* d_ws, size_t ws_size,
                              hipStream_t stream) {
    const int*   h_index       = (const int*)d_in[0];
    const int*   r_index       = (const int*)d_in[1];
    const int*   t_index       = (const int*)d_in[2];
    const float* hidden_states = (const float*)d_in[3];
    const int*   edge_index    = (const int*)d_in[5];
    const int*   edge_attr     = (const int*)d_in[6];
    const float* text          = (const float*)d_in[7];
    const float* rel_table     = (const float*)d_in[9];
    const float* W_lin         = (const float*)d_in[10];
    const float* b_lin         = (const float*)d_in[11];
    const float* W1            = (const float*)d_in[12];
    const float* b1            = (const float*)d_in[13];
    const float* W2            = (const float*)d_in[14];
    const float* b2            = (const float*)d_in[15];
    const float* rel_w         = (const float*)d_in[16];
    const float* conv_W        = (const float*)d_in[17];
    const float* conv_b        = (const float*)d_in[18];

    char* ws = (char*)d_ws;
    size_t off = 0;
    auto carve = [&](size_t bytes) -> char* {
        char* p = ws + off;
        off = (off + bytes + 255) & ~(size_t)255;
        return p;
    };
    float*    scalars = (float*)carve(256);                 // [0]=thr [1]=THR [3]=pna_mean
    unsigned* state   = (unsigned*)carve(256);              // radix select state
    unsigned* countp  = (unsigned*)carve(256);
    float*    qh      = (float*)carve(256);
    unsigned* ghn     = (unsigned*)carve(1024);
    unsigned* ghw     = (unsigned*)carve(1024);
    float*    score   = (float*)carve((size_t)NT * 4);
    float*    hidden  = (float*)carve((size_t)NT * 64 * 4);
    float*    updc    = (float*)carve((size_t)NT * 64 * 4);
    int*      list    = (int*)carve((size_t)NT * 4);
    unsigned* degb    = (unsigned*)carve((size_t)N_NODES * 4);
    unsigned* degbt   = (unsigned*)carve((size_t)NT * 4);
    unsigned* rowptr  = (unsigned*)carve((size_t)(N_NODES + 1) * 4);
    unsigned* cursor  = (unsigned*)carve((size_t)N_NODES * 4);
    unsigned* inedge  = (unsigned*)carve((size_t)2 * E_EDGES * 4);
    if (off > ws_size) return;

    hipMemsetAsync(scalars, 0, 256, stream);
    hipMemsetAsync(ghn, 0, 1024, stream);
    hipMemsetAsync(ghw, 0, 1024, stream);
    hipMemsetAsync(score, 0, (size_t)NT * 4, stream);
    hipMemsetAsync(degb, 0, (size_t)N_NODES * 4, stream);

    count_deg<<<(E_EDGES + 255) / 256, 256, 0, stream>>>(edge_index, degb);
    scan_degrees<<<1, 1024, 0, stream>>>(degb, rowptr, cursor);
    scatter_edges<<<(E_EDGES + 255) / 256, 256, 0, stream>>>(edge_index, edge_attr, cursor, inedge);
    tile_degb<<<(NT + 255) / 256, 256, 0, stream>>>(degb, degbt);
    pna_kernel<<<1, 1024, 0, stream>>>(degb, scalars);
    init_hidden<<<(NT * 64 + 255) / 256, 256, 0, stream>>>(text, hidden);
    init_heads<<<1, 256, 0, stream>>>(h_index, r_index, hidden_states, rel_table,
                                      W_lin, b_lin, W1, b1, W2, b2, hidden, score, qh);

    for (int l = 0; l < 3; ++l) {
        for (int p = 0; p < 4; ++p) {
            hist_pass<<<40, 256, 0, stream>>>(score, degbt, ghn, ghw, state, p);
            pick_pass<<<1, 256, 0, stream>>>(ghn, ghw, state, scalars, countp, p);
        }
        compact<<<(NT + 255) / 256, 256, 0, stream>>>(score, degbt, scalars, countp, list);
        node_update<<<1250, 256, 0, stream>>>(score, hidden, rowptr, inedge, rel_w,
                                              conv_W, conv_b, scalars, countp, list, updc, l);
        apply_score<<<1250, 256, 0, stream>>>(hidden, updc, score, countp, list,
                                              W_lin, qh, W1, b1, W2, b2);
    }
    gather_out<<<1, 64, 0, stream>>>(score, t_index, (float*)d_out);
}

// Round 3
// 633.460 us; speedup vs baseline: 3.0056x; 1.3185x over previous
//
#include <hip/hip_runtime.h>
#include <math.h>

#define N_NODES 10000
#define E_EDGES 50000
#define NT      40000
#define KS_N    4000
#define ES_E    40000
#define WTOT    400000u   // sum of in-degrees over batched graph (2*E*B), constant
#define CHUNK   16384
#define NCHUNK  3

// ---------- helpers ----------
__device__ __forceinline__ unsigned f2u(float f) {
    unsigned b = __float_as_uint(f);
    return (b & 0x80000000u) ? ~b : (b | 0x80000000u);
}
__device__ __forceinline__ float u2f(unsigned u) {
    unsigned b = (u & 0x80000000u) ? (u & 0x7fffffffu) : ~u;
    return __uint_as_float(b);
}
__device__ __forceinline__ float wave_sum64(float x) {
    for (int off = 32; off > 0; off >>= 1) x += __shfl_down(x, off, 64);
    return x;  // valid on lane 0
}

// ---------- graph build ----------
__global__ void count_deg(const int* __restrict__ ei, unsigned* __restrict__ deg) {
    int j = blockIdx.x * 256 + threadIdx.x;
    if (j < E_EDGES) {
        atomicAdd(&deg[ei[j]], 1u);
        atomicAdd(&deg[ei[E_EDGES + j]], 1u);
    }
}

__global__ __launch_bounds__(1024) void scan_degrees(const unsigned* __restrict__ deg,
                                                     unsigned* __restrict__ rowptr,
                                                     unsigned* __restrict__ cursor) {
    __shared__ unsigned wsum[16];
    __shared__ unsigned carry;
    int tid = threadIdx.x, lane = tid & 63, w = tid >> 6;
    if (tid == 0) carry = 0;
    __syncthreads();
    for (int base = 0; base < N_NODES; base += 1024) {
        int i = base + tid;
        unsigned v = (i < N_NODES) ? deg[i] : 0u;
        unsigned x = v;
        for (int off = 1; off < 64; off <<= 1) {
            unsigned y = __shfl_up(x, off, 64);
            if (lane >= off) x += y;
        }
        if (lane == 63) wsum[w] = x;
        __syncthreads();
        if (tid < 16) {
            unsigned s = wsum[tid];
            for (int off = 1; off < 16; off <<= 1) {
                unsigned y = __shfl_up(s, off, 64);
                if (tid >= off) s += y;
            }
            wsum[tid] = s;
        }
        __syncthreads();
        unsigned woff = (w > 0) ? wsum[w - 1] : 0u;
        unsigned excl = carry + woff + x - v;
        if (i < N_NODES) { rowptr[i] = excl; cursor[i] = excl; }
        __syncthreads();
        if (tid == 0) carry += wsum[15];
        __syncthreads();
    }
    if (tid == 0) rowptr[N_NODES] = carry;
}

__global__ void scatter_edges(const int* __restrict__ ei, const int* __restrict__ ea,
                              unsigned* __restrict__ cursor, unsigned* __restrict__ inedge) {
    int j = blockIdx.x * 256 + threadIdx.x;
    if (j < E_EDGES) {
        unsigned s = (unsigned)ei[j];
        unsigned d = (unsigned)ei[E_EDGES + j];
        unsigned a = (unsigned)ea[j];
        unsigned p1 = atomicAdd(&cursor[d], 1u);
        inedge[p1] = s | (a << 16);
        unsigned p2 = atomicAdd(&cursor[s], 1u);
        inedge[p2] = d | (a << 16);
    }
}

__global__ void tile_degb(const unsigned* __restrict__ degb, unsigned* __restrict__ degbt) {
    int v = blockIdx.x * 256 + threadIdx.x;
    if (v < NT) degbt[v] = degb[v % N_NODES];
}

// deterministic single-block pna mean
__global__ __launch_bounds__(1024) void pna_kernel(const unsigned* __restrict__ degb,
                                                   float* __restrict__ scalars) {
    __shared__ float ws[16];
    int tid = threadIdx.x;
    float s = 0.0f;
    for (int i = tid; i < N_NODES; i += 1024) s += logf((float)degb[i] + 1.0f);
    for (int off = 32; off > 0; off >>= 1) s += __shfl_down(s, off, 64);
    if ((tid & 63) == 0) ws[tid >> 6] = s;
    __syncthreads();
    if (tid == 0) {
        float t = 0.0f;
        for (int i = 0; i < 16; ++i) t += ws[i];
        scalars[3] = t / (float)N_NODES;
    }
}

// ---------- init ----------
__global__ void init_hidden(const float* __restrict__ text, float* __restrict__ hidden) {
    int i = blockIdx.x * 256 + threadIdx.x;
    if (i < NT * 64) {
        int v = i >> 6;
        hidden[i] = (v < N_NODES) ? text[i] : 0.0f;
    }
}

__device__ float wave_score_g(float hid, float rel, const float* Wlin, const float* blin,
                              const float* W1, const float* b1, const float* W2, float b2v,
                              int lane) {
    float heur = blin[lane];
    for (int i = 0; i < 64; ++i) heur += __shfl(hid, i, 64) * Wlin[i * 64 + lane];
    for (int i = 0; i < 64; ++i) heur += __shfl(rel, i, 64) * Wlin[(64 + i) * 64 + lane];
    float x = hid * heur;
    float a0 = b1[lane], a1 = b1[64 + lane];
    for (int i = 0; i < 64; ++i) {
        float xv = __shfl(x, i, 64);
        a0 += xv * W1[i * 128 + lane];
        a1 += xv * W1[i * 128 + 64 + lane];
    }
    a0 = fmaxf(a0, 0.0f); a1 = fmaxf(a1, 0.0f);
    float part = a0 * W2[lane] + a1 * W2[64 + lane];
    part = wave_sum64(part);
    part = __shfl(part, 0, 64);
    return part + b2v;
}

__global__ void init_heads(const int* __restrict__ h_index, const int* __restrict__ r_index,
                           const float* __restrict__ hidden_states,
                           const float* __restrict__ rel_table,
                           const float* __restrict__ W_lin, const float* __restrict__ b_lin,
                           const float* __restrict__ W1, const float* __restrict__ b1,
                           const float* __restrict__ W2, const float* __restrict__ b2,
                           float* __restrict__ hidden, float* __restrict__ score,
                           float* __restrict__ qh) {
    __shared__ float q0[64];
    int tid = threadIdx.x, w = tid >> 6, lane = tid & 63;
    int b = w;  // 4 waves, one per batch element
    int h0 = h_index[b * 16] + b * N_NODES;
    float hs  = hidden_states[b * 64 + lane];
    float rel = rel_table[r_index[b * 16] * 64 + lane];
    hidden[h0 * 64 + lane] = hs;
    if (b == 0) q0[lane] = rel;
    float s = wave_score_g(hs, rel, W_lin, b_lin, W1, b1, W2, b2[0], lane);
    if (lane == 0) score[h0] = s;
    __syncthreads();
    if (w == 0) {  // qh[t] = sum_i q0[i]*W_lin[64+i][t] + b_lin[t]
        float acc = b_lin[lane];
        for (int i = 0; i < 64; ++i) acc += q0[i] * W_lin[(64 + i) * 64 + lane];
        qh[lane] = acc;
    }
}

// ---------- dual radix select, pick folded in via last-block pattern ----------
__device__ void block_pick(unsigned h, unsigned r, unsigned* outd, unsigned* outr,
                           unsigned* scr) {
    // 256 threads; exactly one digit d satisfies excl<=r<excl+h. scr >= 8 words.
    int tid = threadIdx.x, lane = tid & 63, w = tid >> 6;
    __syncthreads();
    unsigned x = h;
    for (int off = 1; off < 64; off <<= 1) {
        unsigned y = __shfl_up(x, off, 64);
        if (lane >= off) x += y;
    }
    if (lane == 63) scr[w] = x;
    __syncthreads();
    unsigned woff = 0;
    for (int i = 0; i < 4; ++i) if (i < w) woff += scr[i];
    unsigned excl = woff + x - h;
    if (r >= excl && r < excl + h) { scr[4] = (unsigned)tid; scr[5] = r - excl; }
    __syncthreads();
    *outd = scr[4]; *outr = scr[5];
}

__global__ __launch_bounds__(256) void select_pass(
    const float* __restrict__ score, const unsigned* __restrict__ degbt,
    unsigned* __restrict__ ghn, unsigned* __restrict__ ghw,
    unsigned* __restrict__ state, float* __restrict__ scalars,
    unsigned* __restrict__ countp, int pass) {
    __shared__ unsigned lh[512];
    __shared__ unsigned scr[8];
    __shared__ unsigned sh_last;
    int tid = threadIdx.x;
    lh[tid] = 0; lh[256 + tid] = 0;
    __syncthreads();
    unsigned pn = state[0], pw = state[2];
    int shift = 24 - pass * 8;
    for (int v = blockIdx.x * 256 + tid; v < NT; v += gridDim.x * 256) {
        unsigned key = f2u(score[v]);
        unsigned wg = degbt[v];
        unsigned dig = (key >> shift) & 255u;
        if (pass == 0) {
            atomicAdd(&lh[dig], 1u);
            if (wg) atomicAdd(&lh[256 + dig], wg);
        } else {
            unsigned hi = key >> (shift + 8);
            if (hi == pn) atomicAdd(&lh[dig], 1u);
            if (wg && hi == pw) atomicAdd(&lh[256 + dig], wg);
        }
    }
    __syncthreads();
    if (lh[tid]) atomicAdd(&ghn[tid], lh[tid]);
    if (lh[256 + tid]) atomicAdd(&ghw[tid], lh[256 + tid]);
    __threadfence();
    if (tid == 0) sh_last = atomicAdd(&state[8 + pass], 1u);
    __syncthreads();
    if (sh_last != gridDim.x - 1) return;
    // ---- last block: pick digit for both selects, reset hists ----
    unsigned hn = atomicAdd(&ghn[tid], 0u);
    unsigned hw = atomicAdd(&ghw[tid], 0u);
    ghn[tid] = 0; ghw[tid] = 0;
    unsigned rn, rw_;
    if (pass == 0) { pn = 0; rn = NT - KS_N; pw = 0; rw_ = WTOT - ES_E; }
    else { rn = state[1]; rw_ = state[3]; }
    unsigned dn, rn2, dw, rw2;
    block_pick(hn, rn, &dn, &rn2, scr);
    block_pick(hw, rw_, &dw, &rw2, scr);
    if (tid == 0) {
        pn = (pn << 8) | dn;
        pw = (pw << 8) | dw;
        state[0] = pn; state[1] = rn2; state[2] = pw; state[3] = rw2;
        state[8 + pass] = 0;  // reset arrival counter for next layer
        if (pass == 3) {
            float thr = u2f(pn), thre = u2f(pw);
            scalars[0] = thr;
            scalars[1] = fmaxf(thr, thre);  // effective edge/node threshold
            *countp = 0;
        }
    }
}

// ---------- compact + sigmoid precompute ----------
__global__ void compact_sig(const float* __restrict__ score, const unsigned* __restrict__ degbt,
                            const float* __restrict__ scalars, unsigned* __restrict__ countp,
                            int* __restrict__ list, float* __restrict__ sigp) {
    int v = blockIdx.x * 256 + threadIdx.x;
    if (v >= NT) return;
    float sc = score[v];
    bool pass = sc >= scalars[1];
    float sg = -1.0f;
    if (pass) sg = 1.0f / (1.0f + expf(-sc));
    sigp[v] = sg;
    if (pass && degbt[v] > 0) {
        unsigned p = atomicAdd(countp, 1u);
        list[p] = v;
    }
}

// ---------- per-node edge aggregation: one node per wave, no LDS ----------
__global__ __launch_bounds__(256) void agg_feat(
    const float* __restrict__ sigp, const float* __restrict__ hidden,
    const unsigned* __restrict__ rowptr, const unsigned* __restrict__ inedge,
    const float* __restrict__ rel_w, const float* __restrict__ scalars,
    const unsigned* __restrict__ countp, const int* __restrict__ list,
    float* __restrict__ feat, float* __restrict__ ampatt, int layer, int mbase) {
    int count = (int)*countp;
    int cc = count - mbase; if (cc > CHUNK) cc = CHUNK;
    int tid = threadIdx.x, w = tid >> 6, lane = tid & 63;
    int li = blockIdx.x * 4 + w;
    if (li >= cc) return;
    int v = list[mbase + li];
    int b = v / N_NODES;
    int boff = b * N_NODES;
    int n = v - boff;
    const float* rw = rel_w + (size_t)layer * 400 * 64;
    unsigned r0 = rowptr[n], r1 = rowptr[n + 1];
    float sum = 0.f, sq = 0.f, mx = -INFINITY, mn = INFINITY;
    int cnt = 0;
    #pragma unroll 2
    for (unsigned e = r0; e < r1; ++e) {
        unsigned pk = inedge[e];
        int src = (int)(pk & 0xffffu) + boff;
        float sg = sigp[src];
        float h  = hidden[((size_t)src << 6) + lane];
        float rv = rw[((size_t)(pk >> 16) << 6) + lane];
        bool valid = sg >= 0.0f;
        float mval = sg * h * rv;
        if (valid) { sum += mval; sq += mval * mval; }
        mx = fmaxf(mx, valid ? mval : -INFINITY);
        mn = fminf(mn, valid ? mval : INFINITY);
        cnt += valid ? 1 : 0;
    }
    float denom = cnt > 0 ? (float)cnt : 1.0f;
    float mean = sum / denom;
    float sd = sqrtf(fmaxf(sq / denom - mean * mean, 0.0f) + 1e-6f);
    float* fr = feat + ((size_t)li << 8);
    fr[lane]        = mean;
    fr[64 + lane]   = cnt > 0 ? mx : 0.0f;
    fr[128 + lane]  = cnt > 0 ? mn : 0.0f;
    fr[192 + lane]  = sd;
    if (lane == 0) {
        float pna = scalars[3];
        float sl = logf((float)cnt + 1.0f);
        ampatt[li * 2]     = sl / pna;
        ampatt[li * 2 + 1] = pna / (sl + 1e-6f);
    }
}

// ---------- tiled fp32 GEMM: upd[64 x 64] = feat[64 x 256] @ (W0 + amp*W1 + att*W2) ----------
#define FMA4(C, av, bv) { C[0] += av * bv.x; C[1] += av * bv.y; C[2] += av * bv.z; C[3] += av * bv.w; }

__global__ __launch_bounds__(256) void gemm_upd(
    const float* __restrict__ conv_W, const float* __restrict__ conv_b,
    const unsigned* __restrict__ countp, const float* __restrict__ feat,
    const float* __restrict__ ampatt, float* __restrict__ updc,
    int layer, int mbase) {
    __shared__ float sA[32][68];
    __shared__ float sB[32][196];
    __shared__ float sAmp[64], sAtt[64];
    int count = (int)*countp;
    int cc = count - mbase; if (cc > CHUNK) cc = CHUNK;
    int m0 = blockIdx.x * 64;
    if (m0 >= cc) return;
    int tid = threadIdx.x;
    if (tid < 64) {
        int rl = m0 + tid;
        float a = 0.f, t = 0.f;
        if (rl < cc) { a = ampatt[rl * 2]; t = ampatt[rl * 2 + 1]; }
        sAmp[tid] = a; sAtt[tid] = t;
    }
    int mg = tid >> 4, ng = tid & 15;
    int j0 = ng * 4;
    float c0[4][4] = {}, c1[4][4] = {}, c2[4][4] = {};
    const float* Wl = conv_W + (size_t)layer * 768 * 64;
    const float4* feat4 = (const float4*)feat;
    for (int k0 = 0; k0 < 256; k0 += 32) {
        __syncthreads();
        #pragma unroll
        for (int it = 0; it < 2; ++it) {                 // A tile 64 x 32, stored [k][m]
            int fi = it * 256 + tid;
            int row = fi >> 3, kq = fi & 7;
            float4 va = feat4[(((size_t)(m0 + row)) << 6) + (k0 >> 2) + kq];
            sA[kq * 4 + 0][row] = va.x; sA[kq * 4 + 1][row] = va.y;
            sA[kq * 4 + 2][row] = va.z; sA[kq * 4 + 3][row] = va.w;
        }
        #pragma unroll
        for (int it = 0; it < 6; ++it) {                 // B tile 32 x 192
            int fi = it * 256 + tid;
            int rr = fi >> 4, q = fi & 15;
            int part = rr >> 5, kk = rr & 31;
            float4 vb = *(const float4*)(Wl + (((size_t)(part * 256 + k0 + kk)) << 6) + q * 4);
            float* d = &sB[kk][part * 64 + q * 4];
            d[0] = vb.x; d[1] = vb.y; d[2] = vb.z; d[3] = vb.w;
        }
        __syncthreads();
        #pragma unroll 4
        for (int kk = 0; kk < 32; ++kk) {
            float4 a  = *(const float4*)&sA[kk][mg * 4];
            float4 b0 = *(const float4*)&sB[kk][j0];
            float4 b1 = *(const float4*)&sB[kk][64 + j0];
            float4 b2 = *(const float4*)&sB[kk][128 + j0];
            FMA4(c0[0], a.x, b0) FMA4(c0[1], a.y, b0) FMA4(c0[2], a.z, b0) FMA4(c0[3], a.w, b0)
            FMA4(c1[0], a.x, b1) FMA4(c1[1], a.y, b1) FMA4(c1[2], a.z, b1) FMA4(c1[3], a.w, b1)
            FMA4(c2[0], a.x, b2) FMA4(c2[1], a.y, b2) FMA4(c2[2], a.z, b2) FMA4(c2[3], a.w, b2)
        }
    }
    const float4 bias = *(const float4*)(conv_b + layer * 64 + j0);
    #pragma unroll
    for (int mi = 0; mi < 4; ++mi) {
        int ml = mg * 4 + mi;
        int rl = m0 + ml;
        if (rl < cc) {
            float amp = sAmp[ml], att = sAtt[ml];
            float4 o;
            o.x = fmaxf(c0[mi][0] + amp * c1[mi][0] + att * c2[mi][0] + bias.x, 0.0f);
            o.y = fmaxf(c0[mi][1] + amp * c1[mi][1] + att * c2[mi][1] + bias.y, 0.0f);
            o.z = fmaxf(c0[mi][2] + amp * c1[mi][2] + att * c2[mi][2] + bias.z, 0.0f);
            o.w = fmaxf(c0[mi][3] + amp * c1[mi][3] + att * c2[mi][3] + bias.w, 0.0f);
            *(float4*)(updc + (((size_t)(mbase + rl)) << 6) + j0) = o;
        }
    }
}

// ---------- apply update + score MLP over compacted list ----------
__global__ __launch_bounds__(256) void apply_score(
    float* __restrict__ hidden, const float* __restrict__ updc,
    float* __restrict__ score, const unsigned* __restrict__ countp,
    const int* __restrict__ list,
    const float* __restrict__ W_lin, const float* __restrict__ qh,
    const float* __restrict__ W1, const float* __restrict__ b1,
    const float* __restrict__ W2, const float* __restrict__ b2) {
    __shared__ float sWl[4096];
    __shared__ float sW1[8192];
    __shared__ float sW2[128];
    __shared__ float sB1[128];
    __shared__ float sQh[64];
    int count = (int)*countp;
    if ((int)blockIdx.x * 4 >= count) return;
    int tid = threadIdx.x;
    for (int i = tid; i < 4096; i += 256) sWl[i] = W_lin[i];
    for (int i = tid; i < 8192; i += 256) sW1[i] = W1[i];
    if (tid < 128) { sW2[tid] = W2[tid]; sB1[tid] = b1[tid]; }
    if (tid < 64) sQh[tid] = qh[tid];
    __syncthreads();
    float b2v = b2[0];
    int w = tid >> 6, lane = tid & 63;
    for (int idx = blockIdx.x * 4 + w; idx < count; idx += gridDim.x * 4) {
        int v = list[idx];
        float h = hidden[((size_t)v << 6) + lane] + updc[((size_t)idx << 6) + lane];
        hidden[((size_t)v << 6) + lane] = h;
        float heur = sQh[lane];
        #pragma unroll 4
        for (int i = 0; i < 64; ++i) heur += __shfl(h, i, 64) * sWl[i * 64 + lane];
        float x = h * heur;
        float a0 = sB1[lane], a1 = sB1[64 + lane];
        #pragma unroll 4
        for (int i = 0; i < 64; ++i) {
            float xv = __shfl(x, i, 64);
            a0 += xv * sW1[i * 128 + lane];
            a1 += xv * sW1[i * 128 + 64 + lane];
        }
        a0 = fmaxf(a0, 0.0f); a1 = fmaxf(a1, 0.0f);
        float part = a0 * sW2[lane] + a1 * sW2[64 + lane];
        part = wave_sum64(part);
        if (lane == 0) score[v] = part + b2v;
    }
}

// ---------- output gather ----------
__global__ void gather_out(const float* __restrict__ score, const int* __restrict__ t_index,
                           float* __restrict__ out) {
    int i = threadIdx.x;  // 64 threads
    int b = i >> 4;
    out[i] = score[t_index[i] + b * N_NODES];
}

// ---------- launcher ----------
extern "C" void kernel_launch(void* const* d_in, const int* in_sizes, int n_in,
                              void* d_out, int out_size, void* d_ws, size_t ws_size,
                              hipStream_t stream) {
    const int*   h_index       = (const int*)d_in[0];
    const int*   r_index       = (const int*)d_in[1];
    const int*   t_index       = (const int*)d_in[2];
    const float* hidden_states = (const float*)d_in[3];
    const int*   edge_index    = (const int*)d_in[5];
    const int*   edge_attr     = (const int*)d_in[6];
    const float* text          = (const float*)d_in[7];
    const float* rel_table     = (const float*)d_in[9];
    const float* W_lin         = (const float*)d_in[10];
    const float* b_lin         = (const float*)d_in[11];
    const float* W1            = (const float*)d_in[12];
    const float* b1            = (const float*)d_in[13];
    const float* W2            = (const float*)d_in[14];
    const float* b2            = (const float*)d_in[15];
    const float* rel_w         = (const float*)d_in[16];
    const float* conv_W        = (const float*)d_in[17];
    const float* conv_b        = (const float*)d_in[18];

    char* ws = (char*)d_ws;
    size_t off = 0;
    auto carve = [&](size_t bytes) -> char* {
        char* p = ws + off;
        off = (off + bytes + 255) & ~(size_t)255;
        return p;
    };
    float*    scalars = (float*)carve(256);                 // [0]=thr [1]=THR [3]=pna_mean
    unsigned* state   = (unsigned*)carve(256);              // [0..3]=radix state [8..11]=arrival
    unsigned* countp  = (unsigned*)carve(256);
    float*    qh      = (float*)carve(256);
    unsigned* ghn     = (unsigned*)carve(1024);
    unsigned* ghw     = (unsigned*)carve(1024);
    float*    score   = (float*)carve((size_t)NT * 4);
    float*    sigp    = (float*)carve((size_t)NT * 4);
    float*    hidden  = (float*)carve((size_t)NT * 64 * 4);
    float*    updc    = (float*)carve((size_t)NT * 64 * 4);
    float*    feat    = (float*)carve((size_t)CHUNK * 256 * 4);
    float*    ampatt  = (float*)carve((size_t)CHUNK * 2 * 4);
    int*      list    = (int*)carve((size_t)NT * 4);
    unsigned* degb    = (unsigned*)carve((size_t)N_NODES * 4);
    unsigned* degbt   = (unsigned*)carve((size_t)NT * 4);
    unsigned* rowptr  = (unsigned*)carve((size_t)(N_NODES + 1) * 4);
    unsigned* cursor  = (unsigned*)carve((size_t)N_NODES * 4);
    unsigned* inedge  = (unsigned*)carve((size_t)2 * E_EDGES * 4);
    if (off > ws_size) return;

    hipMemsetAsync(scalars, 0, 256, stream);
    hipMemsetAsync(state, 0, 256, stream);
    hipMemsetAsync(ghn, 0, 1024, stream);
    hipMemsetAsync(ghw, 0, 1024, stream);
    hipMemsetAsync(score, 0, (size_t)NT * 4, stream);
    hipMemsetAsync(degb, 0, (size_t)N_NODES * 4, stream);

    count_deg<<<(E_EDGES + 255) / 256, 256, 0, stream>>>(edge_index, degb);
    scan_degrees<<<1, 1024, 0, stream>>>(degb, rowptr, cursor);
    scatter_edges<<<(E_EDGES + 255) / 256, 256, 0, stream>>>(edge_index, edge_attr, cursor, inedge);
    tile_degb<<<(NT + 255) / 256, 256, 0, stream>>>(degb, degbt);
    pna_kernel<<<1, 1024, 0, stream>>>(degb, scalars);
    init_hidden<<<(NT * 64 + 255) / 256, 256, 0, stream>>>(text, hidden);
    init_heads<<<1, 256, 0, stream>>>(h_index, r_index, hidden_states, rel_table,
                                      W_lin, b_lin, W1, b1, W2, b2, hidden, score, qh);

    for (int l = 0; l < 3; ++l) {
        for (int p = 0; p < 4; ++p)
            select_pass<<<40, 256, 0, stream>>>(score, degbt, ghn, ghw, state,
                                                scalars, countp, p);
        compact_sig<<<(NT + 255) / 256, 256, 0, stream>>>(score, degbt, scalars,
                                                          countp, list, sigp);
        for (int c = 0; c < NCHUNK; ++c) {
            int mbase = c * CHUNK;
            agg_feat<<<CHUNK / 4, 256, 0, stream>>>(sigp, hidden, rowptr, inedge, rel_w,
                                                    scalars, countp, list, feat, ampatt,
                                                    l, mbase);
            gemm_upd<<<CHUNK / 64, 256, 0, stream>>>(conv_W, conv_b, countp, feat, ampatt,
                                                     updc, l, mbase);
        }
        apply_score<<<2500, 256, 0, stream>>>(hidden, updc, score, countp, list,
                                              W_lin, qh, W1, b1, W2, b2);
    }
    gather_out<<<1, 64, 0, stream>>>(score, t_index, (float*)d_out);
}

// Round 4
// 565.270 us; speedup vs baseline: 3.3682x; 1.1206x over previous
//
#include <hip/hip_runtime.h>
#include <math.h>

#define N_NODES 10000
#define E_EDGES 50000
#define NT      40000
#define KS_N    4000
#define ES_E    40000
#define WTOT    400000u   // sum of in-degrees over batched graph (2*E*B), constant
#define CHUNK   16384
#define NCHUNK  3

// ---------- helpers ----------
__device__ __forceinline__ unsigned f2u(float f) {
    unsigned b = __float_as_uint(f);
    return (b & 0x80000000u) ? ~b : (b | 0x80000000u);
}
__device__ __forceinline__ float u2f(unsigned u) {
    unsigned b = (u & 0x80000000u) ? (u & 0x7fffffffu) : ~u;
    return __uint_as_float(b);
}
__device__ __forceinline__ float wave_sum64(float x) {
    for (int off = 32; off > 0; off >>= 1) x += __shfl_down(x, off, 64);
    return x;  // valid on lane 0
}

// ---------- graph build ----------
__global__ void count_deg(const int* __restrict__ ei, unsigned* __restrict__ deg) {
    int j = blockIdx.x * 256 + threadIdx.x;
    if (j < E_EDGES) {
        atomicAdd(&deg[ei[j]], 1u);
        atomicAdd(&deg[ei[E_EDGES + j]], 1u);
    }
}

__global__ __launch_bounds__(1024) void scan_degrees(const unsigned* __restrict__ deg,
                                                     unsigned* __restrict__ rowptr,
                                                     unsigned* __restrict__ cursor) {
    __shared__ unsigned wsum[16];
    __shared__ unsigned carry;
    int tid = threadIdx.x, lane = tid & 63, w = tid >> 6;
    if (tid == 0) carry = 0;
    __syncthreads();
    for (int base = 0; base < N_NODES; base += 1024) {
        int i = base + tid;
        unsigned v = (i < N_NODES) ? deg[i] : 0u;
        unsigned x = v;
        for (int off = 1; off < 64; off <<= 1) {
            unsigned y = __shfl_up(x, off, 64);
            if (lane >= off) x += y;
        }
        if (lane == 63) wsum[w] = x;
        __syncthreads();
        if (tid < 16) {
            unsigned s = wsum[tid];
            for (int off = 1; off < 16; off <<= 1) {
                unsigned y = __shfl_up(s, off, 64);
                if (tid >= off) s += y;
            }
            wsum[tid] = s;
        }
        __syncthreads();
        unsigned woff = (w > 0) ? wsum[w - 1] : 0u;
        unsigned excl = carry + woff + x - v;
        if (i < N_NODES) { rowptr[i] = excl; cursor[i] = excl; }
        __syncthreads();
        if (tid == 0) carry += wsum[15];
        __syncthreads();
    }
    if (tid == 0) rowptr[N_NODES] = carry;
}

__global__ void scatter_edges(const int* __restrict__ ei, const int* __restrict__ ea,
                              unsigned* __restrict__ cursor, unsigned* __restrict__ inedge) {
    int j = blockIdx.x * 256 + threadIdx.x;
    if (j < E_EDGES) {
        unsigned s = (unsigned)ei[j];
        unsigned d = (unsigned)ei[E_EDGES + j];
        unsigned a = (unsigned)ea[j];
        unsigned p1 = atomicAdd(&cursor[d], 1u);
        inedge[p1] = s | (a << 16);
        unsigned p2 = atomicAdd(&cursor[s], 1u);
        inedge[p2] = d | (a << 16);
    }
}

__global__ void tile_degb(const unsigned* __restrict__ degb, unsigned* __restrict__ degbt) {
    int v = blockIdx.x * 256 + threadIdx.x;
    if (v < NT) degbt[v] = degb[v % N_NODES];
}

// deterministic single-block pna mean
__global__ __launch_bounds__(1024) void pna_kernel(const unsigned* __restrict__ degb,
                                                   float* __restrict__ scalars) {
    __shared__ float ws[16];
    int tid = threadIdx.x;
    float s = 0.0f;
    for (int i = tid; i < N_NODES; i += 1024) s += logf((float)degb[i] + 1.0f);
    for (int off = 32; off > 0; off >>= 1) s += __shfl_down(s, off, 64);
    if ((tid & 63) == 0) ws[tid >> 6] = s;
    __syncthreads();
    if (tid == 0) {
        float t = 0.0f;
        for (int i = 0; i < 16; ++i) t += ws[i];
        scalars[3] = t / (float)N_NODES;
    }
}

// ---------- init ----------
__global__ void init_hidden(const float* __restrict__ text, float* __restrict__ hidden) {
    int i = blockIdx.x * 256 + threadIdx.x;
    if (i < NT * 64) {
        int v = i >> 6;
        hidden[i] = (v < N_NODES) ? text[i] : 0.0f;
    }
}

__device__ float wave_score_g(float hid, float rel, const float* Wlin, const float* blin,
                              const float* W1, const float* b1, const float* W2, float b2v,
                              int lane) {
    float heur = blin[lane];
    for (int i = 0; i < 64; ++i) heur += __shfl(hid, i, 64) * Wlin[i * 64 + lane];
    for (int i = 0; i < 64; ++i) heur += __shfl(rel, i, 64) * Wlin[(64 + i) * 64 + lane];
    float x = hid * heur;
    float a0 = b1[lane], a1 = b1[64 + lane];
    for (int i = 0; i < 64; ++i) {
        float xv = __shfl(x, i, 64);
        a0 += xv * W1[i * 128 + lane];
        a1 += xv * W1[i * 128 + 64 + lane];
    }
    a0 = fmaxf(a0, 0.0f); a1 = fmaxf(a1, 0.0f);
    float part = a0 * W2[lane] + a1 * W2[64 + lane];
    part = wave_sum64(part);
    part = __shfl(part, 0, 64);
    return part + b2v;
}

__global__ void init_heads(const int* __restrict__ h_index, const int* __restrict__ r_index,
                           const float* __restrict__ hidden_states,
                           const float* __restrict__ rel_table,
                           const float* __restrict__ W_lin, const float* __restrict__ b_lin,
                           const float* __restrict__ W1, const float* __restrict__ b1,
                           const float* __restrict__ W2, const float* __restrict__ b2,
                           float* __restrict__ hidden, float* __restrict__ score,
                           float* __restrict__ qh) {
    __shared__ float q0[64];
    int tid = threadIdx.x, w = tid >> 6, lane = tid & 63;
    int b = w;  // 4 waves, one per batch element
    int h0 = h_index[b * 16] + b * N_NODES;
    float hs  = hidden_states[b * 64 + lane];
    float rel = rel_table[r_index[b * 16] * 64 + lane];
    hidden[h0 * 64 + lane] = hs;
    if (b == 0) q0[lane] = rel;
    float s = wave_score_g(hs, rel, W_lin, b_lin, W1, b1, W2, b2[0], lane);
    if (lane == 0) score[h0] = s;
    __syncthreads();
    if (w == 0) {  // qh[t] = sum_i q0[i]*W_lin[64+i][t] + b_lin[t]
        float acc = b_lin[lane];
        for (int i = 0; i < 64; ++i) acc += q0[i] * W_lin[(64 + i) * 64 + lane];
        qh[lane] = acc;
    }
}

// ---------- dual radix select, pick folded in via last-block pattern ----------
__device__ void block_pick(unsigned h, unsigned r, unsigned* outd, unsigned* outr,
                           unsigned* scr) {
    // 256 threads; exactly one digit d satisfies excl<=r<excl+h. scr >= 8 words.
    int tid = threadIdx.x, lane = tid & 63, w = tid >> 6;
    __syncthreads();
    unsigned x = h;
    for (int off = 1; off < 64; off <<= 1) {
        unsigned y = __shfl_up(x, off, 64);
        if (lane >= off) x += y;
    }
    if (lane == 63) scr[w] = x;
    __syncthreads();
    unsigned woff = 0;
    for (int i = 0; i < 4; ++i) if (i < w) woff += scr[i];
    unsigned excl = woff + x - h;
    if (r >= excl && r < excl + h) { scr[4] = (unsigned)tid; scr[5] = r - excl; }
    __syncthreads();
    *outd = scr[4]; *outr = scr[5];
}

__global__ __launch_bounds__(256) void select_pass(
    const float* __restrict__ score, const unsigned* __restrict__ degbt,
    unsigned* __restrict__ ghn, unsigned* __restrict__ ghw,
    unsigned* __restrict__ state, float* __restrict__ scalars,
    unsigned* __restrict__ countp, int pass) {
    __shared__ unsigned lh[512];
    __shared__ unsigned scr[8];
    __shared__ unsigned sh_last;
    int tid = threadIdx.x;
    lh[tid] = 0; lh[256 + tid] = 0;
    __syncthreads();
    unsigned pn = state[0], pw = state[2];
    int shift = 24 - pass * 8;
    for (int v = blockIdx.x * 256 + tid; v < NT; v += gridDim.x * 256) {
        unsigned key = f2u(score[v]);
        unsigned wg = degbt[v];
        unsigned dig = (key >> shift) & 255u;
        if (pass == 0) {
            atomicAdd(&lh[dig], 1u);
            if (wg) atomicAdd(&lh[256 + dig], wg);
        } else {
            unsigned hi = key >> (shift + 8);
            if (hi == pn) atomicAdd(&lh[dig], 1u);
            if (wg && hi == pw) atomicAdd(&lh[256 + dig], wg);
        }
    }
    __syncthreads();
    if (lh[tid]) atomicAdd(&ghn[tid], lh[tid]);
    if (lh[256 + tid]) atomicAdd(&ghw[tid], lh[256 + tid]);
    __threadfence();
    if (tid == 0) sh_last = atomicAdd(&state[8 + pass], 1u);
    __syncthreads();
    if (sh_last != gridDim.x - 1) return;
    // ---- last block: pick digit for both selects, reset hists ----
    unsigned hn = atomicAdd(&ghn[tid], 0u);
    unsigned hw = atomicAdd(&ghw[tid], 0u);
    ghn[tid] = 0; ghw[tid] = 0;
    unsigned rn, rw_;
    if (pass == 0) { pn = 0; rn = NT - KS_N; pw = 0; rw_ = WTOT - ES_E; }
    else { rn = state[1]; rw_ = state[3]; }
    unsigned dn, rn2, dw, rw2;
    block_pick(hn, rn, &dn, &rn2, scr);
    block_pick(hw, rw_, &dw, &rw2, scr);
    if (tid == 0) {
        pn = (pn << 8) | dn;
        pw = (pw << 8) | dw;
        state[0] = pn; state[1] = rn2; state[2] = pw; state[3] = rw2;
        state[8 + pass] = 0;  // reset arrival counter for next layer
        if (pass == 3) {
            float thr = u2f(pn), thre = u2f(pw);
            scalars[0] = thr;
            scalars[1] = fmaxf(thr, thre);  // effective edge/node threshold
            *countp = 0;
        }
    }
}

// ---------- compact + sigmoid precompute ----------
__global__ void compact_sig(const float* __restrict__ score, const unsigned* __restrict__ degbt,
                            const float* __restrict__ scalars, unsigned* __restrict__ countp,
                            int* __restrict__ list, float* __restrict__ sigp) {
    int v = blockIdx.x * 256 + threadIdx.x;
    if (v >= NT) return;
    float sc = score[v];
    bool pass = sc >= scalars[1];
    float sg = -1.0f;
    if (pass) sg = 1.0f / (1.0f + expf(-sc));
    sigp[v] = sg;
    if (pass && degbt[v] > 0) {
        unsigned p = atomicAdd(countp, 1u);
        list[p] = v;
    }
}

// ---------- per-node edge aggregation: one node per wave, no LDS ----------
__global__ __launch_bounds__(256) void agg_feat(
    const float* __restrict__ sigp, const float* __restrict__ hidden,
    const unsigned* __restrict__ rowptr, const unsigned* __restrict__ inedge,
    const float* __restrict__ rel_w, const float* __restrict__ scalars,
    const unsigned* __restrict__ countp, const int* __restrict__ list,
    float* __restrict__ feat, float* __restrict__ ampatt, int layer, int mbase) {
    int count = (int)*countp;
    int cc = count - mbase; if (cc > CHUNK) cc = CHUNK;
    int tid = threadIdx.x, w = tid >> 6, lane = tid & 63;
    int li = blockIdx.x * 4 + w;
    if (li >= cc) return;
    int v = list[mbase + li];
    int b = v / N_NODES;
    int boff = b * N_NODES;
    int n = v - boff;
    const float* rw = rel_w + (size_t)layer * 400 * 64;
    unsigned r0 = rowptr[n], r1 = rowptr[n + 1];
    float sum = 0.f, sq = 0.f, mx = -INFINITY, mn = INFINITY;
    int cnt = 0;
    #pragma unroll 2
    for (unsigned e = r0; e < r1; ++e) {
        unsigned pk = inedge[e];
        int src = (int)(pk & 0xffffu) + boff;
        float sg = sigp[src];
        float h  = hidden[((size_t)src << 6) + lane];
        float rv = rw[((size_t)(pk >> 16) << 6) + lane];
        bool valid = sg >= 0.0f;
        float mval = sg * h * rv;
        if (valid) { sum += mval; sq += mval * mval; }
        mx = fmaxf(mx, valid ? mval : -INFINITY);
        mn = fminf(mn, valid ? mval : INFINITY);
        cnt += valid ? 1 : 0;
    }
    float denom = cnt > 0 ? (float)cnt : 1.0f;
    float mean = sum / denom;
    float sd = sqrtf(fmaxf(sq / denom - mean * mean, 0.0f) + 1e-6f);
    float* fr = feat + ((size_t)li << 8);
    fr[lane]        = mean;
    fr[64 + lane]   = cnt > 0 ? mx : 0.0f;
    fr[128 + lane]  = cnt > 0 ? mn : 0.0f;
    fr[192 + lane]  = sd;
    if (lane == 0) {
        float pna = scalars[3];
        float sl = logf((float)cnt + 1.0f);
        ampatt[li * 2]     = sl / pna;
        ampatt[li * 2 + 1] = pna / (sl + 1e-6f);
    }
}

// ---------- tiled fp32 GEMM: upd[64 x 64] = feat[64 x 256] @ (W0 + amp*W1 + att*W2) ----------
#define FMA4(C, av, bv) { C[0] += av * bv.x; C[1] += av * bv.y; C[2] += av * bv.z; C[3] += av * bv.w; }

__global__ __launch_bounds__(256) void gemm_upd(
    const float* __restrict__ conv_W, const float* __restrict__ conv_b,
    const unsigned* __restrict__ countp, const float* __restrict__ feat,
    const float* __restrict__ ampatt, float* __restrict__ updc,
    int layer, int mbase) {
    __shared__ float sA[32][68];
    __shared__ float sB[32][196];
    __shared__ float sAmp[64], sAtt[64];
    int count = (int)*countp;
    int cc = count - mbase; if (cc > CHUNK) cc = CHUNK;
    int m0 = blockIdx.x * 64;
    if (m0 >= cc) return;
    int tid = threadIdx.x;
    if (tid < 64) {
        int rl = m0 + tid;
        float a = 0.f, t = 0.f;
        if (rl < cc) { a = ampatt[rl * 2]; t = ampatt[rl * 2 + 1]; }
        sAmp[tid] = a; sAtt[tid] = t;
    }
    int mg = tid >> 4, ng = tid & 15;
    int j0 = ng * 4;
    float c0[4][4] = {}, c1[4][4] = {}, c2[4][4] = {};
    const float* Wl = conv_W + (size_t)layer * 768 * 64;
    const float4* feat4 = (const float4*)feat;
    for (int k0 = 0; k0 < 256; k0 += 32) {
        __syncthreads();
        #pragma unroll
        for (int it = 0; it < 2; ++it) {                 // A tile 64 x 32, stored [k][m]
            int fi = it * 256 + tid;
            int row = fi >> 3, kq = fi & 7;
            float4 va = feat4[(((size_t)(m0 + row)) << 6) + (k0 >> 2) + kq];
            sA[kq * 4 + 0][row] = va.x; sA[kq * 4 + 1][row] = va.y;
            sA[kq * 4 + 2][row] = va.z; sA[kq * 4 + 3][row] = va.w;
        }
        #pragma unroll
        for (int it = 0; it < 6; ++it) {                 // B tile 32 x 192
            int fi = it * 256 + tid;
            int rr = fi >> 4, q = fi & 15;
            int part = rr >> 5, kk = rr & 31;
            float4 vb = *(const float4*)(Wl + (((size_t)(part * 256 + k0 + kk)) << 6) + q * 4);
            float* d = &sB[kk][part * 64 + q * 4];
            d[0] = vb.x; d[1] = vb.y; d[2] = vb.z; d[3] = vb.w;
        }
        __syncthreads();
        #pragma unroll 4
        for (int kk = 0; kk < 32; ++kk) {
            float4 a  = *(const float4*)&sA[kk][mg * 4];
            float4 b0 = *(const float4*)&sB[kk][j0];
            float4 b1 = *(const float4*)&sB[kk][64 + j0];
            float4 b2 = *(const float4*)&sB[kk][128 + j0];
            FMA4(c0[0], a.x, b0) FMA4(c0[1], a.y, b0) FMA4(c0[2], a.z, b0) FMA4(c0[3], a.w, b0)
            FMA4(c1[0], a.x, b1) FMA4(c1[1], a.y, b1) FMA4(c1[2], a.z, b1) FMA4(c1[3], a.w, b1)
            FMA4(c2[0], a.x, b2) FMA4(c2[1], a.y, b2) FMA4(c2[2], a.z, b2) FMA4(c2[3], a.w, b2)
        }
    }
    const float4 bias = *(const float4*)(conv_b + layer * 64 + j0);
    #pragma unroll
    for (int mi = 0; mi < 4; ++mi) {
        int ml = mg * 4 + mi;
        int rl = m0 + ml;
        if (rl < cc) {
            float amp = sAmp[ml], att = sAtt[ml];
            float4 o;
            o.x = fmaxf(c0[mi][0] + amp * c1[mi][0] + att * c2[mi][0] + bias.x, 0.0f);
            o.y = fmaxf(c0[mi][1] + amp * c1[mi][1] + att * c2[mi][1] + bias.y, 0.0f);
            o.z = fmaxf(c0[mi][2] + amp * c1[mi][2] + att * c2[mi][2] + bias.z, 0.0f);
            o.w = fmaxf(c0[mi][3] + amp * c1[mi][3] + att * c2[mi][3] + bias.w, 0.0f);
            *(float4*)(updc + (((size_t)(mbase + rl)) << 6) + j0) = o;
        }
    }
}

// ---------- apply update + score MLP as block-tiled GEMM (64 nodes/block) ----------
// Preserves the exact fp32 accumulation order of the previous wave-serial version:
//   heur_j = qh[j] + sum_{k=0..63} h_k * Wl[k][j]          (k ascending)
//   a_j    = b1[j] + sum_{k=0..63} x_k * W1[k][j]          (k ascending), relu
//   p_j    = a_j*W2[j] + a_{j+64}*W2[j+64]
//   score  = shfl_down-tree(p, 32/16/8/4/2/1) + b2
__global__ __launch_bounds__(256) void apply_score_gemm(
    float* __restrict__ hidden, const float* __restrict__ updc,
    float* __restrict__ score, const unsigned* __restrict__ countp,
    const int* __restrict__ list,
    const float* __restrict__ W_lin, const float* __restrict__ qh,
    const float* __restrict__ W1, const float* __restrict__ b1,
    const float* __restrict__ W2, const float* __restrict__ b2) {
    __shared__ float sH[64][65];   // h tile; reused as p tile in phase 3
    __shared__ float sX[64][65];   // x = h * heur
    int count = (int)*countp;
    int m0 = blockIdx.x * 64;
    if (m0 >= count) return;
    int tid = threadIdx.x;

    // ---- phase 0: load h, add upd, store back, stage in LDS ----
    {
        int q = tid & 15;               // float4 column index
        int mB = tid >> 4;              // 0..15
        #pragma unroll
        for (int r = 0; r < 4; ++r) {
            int m = r * 16 + mB;
            int idx = m0 + m;
            float4 hv = {0.f, 0.f, 0.f, 0.f};
            if (idx < count) {
                int v = list[idx];
                hv = *(const float4*)&hidden[((size_t)v << 6) + q * 4];
                float4 uv = *(const float4*)&updc[((size_t)idx << 6) + q * 4];
                hv.x += uv.x; hv.y += uv.y; hv.z += uv.z; hv.w += uv.w;
                *(float4*)&hidden[((size_t)v << 6) + q * 4] = hv;
            }
            sH[m][q * 4 + 0] = hv.x; sH[m][q * 4 + 1] = hv.y;
            sH[m][q * 4 + 2] = hv.z; sH[m][q * 4 + 3] = hv.w;
        }
    }
    __syncthreads();

    int mg = tid >> 4, ng = tid & 15;
    const float4* Wl4 = (const float4*)W_lin;   // [128][16] float4, rows 0..63 used
    const float4* W14 = (const float4*)W1;      // [64][32] float4
    const float4* qh4 = (const float4*)qh;
    const float4* b14 = (const float4*)b1;
    const float4* W24 = (const float4*)W2;

    // ---- phase 1: heur = H @ Wl + qh ; x = h * heur ----
    {
        float4 qv = qh4[ng];
        float acc[4][4];
        #pragma unroll
        for (int mi = 0; mi < 4; ++mi) {
            acc[mi][0] = qv.x; acc[mi][1] = qv.y; acc[mi][2] = qv.z; acc[mi][3] = qv.w;
        }
        for (int k = 0; k < 64; ++k) {
            float4 bv = Wl4[k * 16 + ng];
            #pragma unroll
            for (int mi = 0; mi < 4; ++mi) {
                float av = sH[mg * 4 + mi][k];
                acc[mi][0] += av * bv.x; acc[mi][1] += av * bv.y;
                acc[mi][2] += av * bv.z; acc[mi][3] += av * bv.w;
            }
        }
        #pragma unroll
        for (int mi = 0; mi < 4; ++mi) {
            int m = mg * 4 + mi;
            #pragma unroll
            for (int ni = 0; ni < 4; ++ni)
                sX[m][ng * 4 + ni] = sH[m][ng * 4 + ni] * acc[mi][ni];
        }
    }
    __syncthreads();

    // ---- phase 2: a = relu(X @ W1 + b1); p = aLo*W2lo + aHi*W2hi ----
    {
        float4 bA = b14[ng], bB = b14[16 + ng];
        float accA[4][4], accB[4][4];
        #pragma unroll
        for (int mi = 0; mi < 4; ++mi) {
            accA[mi][0] = bA.x; accA[mi][1] = bA.y; accA[mi][2] = bA.z; accA[mi][3] = bA.w;
            accB[mi][0] = bB.x; accB[mi][1] = bB.y; accB[mi][2] = bB.z; accB[mi][3] = bB.w;
        }
        for (int k = 0; k < 64; ++k) {
            float4 bvA = W14[k * 32 + ng];
            float4 bvB = W14[k * 32 + 16 + ng];
            #pragma unroll
            for (int mi = 0; mi < 4; ++mi) {
                float av = sX[mg * 4 + mi][k];
                accA[mi][0] += av * bvA.x; accA[mi][1] += av * bvA.y;
                accA[mi][2] += av * bvA.z; accA[mi][3] += av * bvA.w;
                accB[mi][0] += av * bvB.x; accB[mi][1] += av * bvB.y;
                accB[mi][2] += av * bvB.z; accB[mi][3] += av * bvB.w;
            }
        }
        float4 w2A = W24[ng], w2B = W24[16 + ng];
        #pragma unroll
        for (int mi = 0; mi < 4; ++mi) {
            int m = mg * 4 + mi;
            float pA0 = fmaxf(accA[mi][0], 0.f), pB0 = fmaxf(accB[mi][0], 0.f);
            float pA1 = fmaxf(accA[mi][1], 0.f), pB1 = fmaxf(accB[mi][1], 0.f);
            float pA2 = fmaxf(accA[mi][2], 0.f), pB2 = fmaxf(accB[mi][2], 0.f);
            float pA3 = fmaxf(accA[mi][3], 0.f), pB3 = fmaxf(accB[mi][3], 0.f);
            sH[m][ng * 4 + 0] = pA0 * w2A.x + pB0 * w2B.x;
            sH[m][ng * 4 + 1] = pA1 * w2A.y + pB1 * w2B.y;
            sH[m][ng * 4 + 2] = pA2 * w2A.z + pB2 * w2B.z;
            sH[m][ng * 4 + 3] = pA3 * w2A.w + pB3 * w2B.w;
        }
    }
    __syncthreads();

    // ---- phase 3: exact shfl_down tree per row, write score ----
    {
        float b2v = b2[0];
        int w = tid >> 6, lane = tid & 63;
        #pragma unroll 4
        for (int t = 0; t < 16; ++t) {
            int m = w * 16 + t;
            float p = sH[m][lane];
            float s = wave_sum64(p);
            if (lane == 0) {
                int idx = m0 + m;
                if (idx < count) score[list[idx]] = s + b2v;
            }
        }
    }
}

// ---------- output gather ----------
__global__ void gather_out(const float* __restrict__ score, const int* __restrict__ t_index,
                           float* __restrict__ out) {
    int i = threadIdx.x;  // 64 threads
    int b = i >> 4;
    out[i] = score[t_index[i] + b * N_NODES];
}

// ---------- launcher ----------
extern "C" void kernel_launch(void* const* d_in, const int* in_sizes, int n_in,
                              void* d_out, int out_size, void* d_ws, size_t ws_size,
                              hipStream_t stream) {
    const int*   h_index       = (const int*)d_in[0];
    const int*   r_index       = (const int*)d_in[1];
    const int*   t_index       = (const int*)d_in[2];
    const float* hidden_states = (const float*)d_in[3];
    const int*   edge_index    = (const int*)d_in[5];
    const int*   edge_attr     = (const int*)d_in[6];
    const float* text          = (const float*)d_in[7];
    const float* rel_table     = (const float*)d_in[9];
    const float* W_lin         = (const float*)d_in[10];
    const float* b_lin         = (const float*)d_in[11];
    const float* W1            = (const float*)d_in[12];
    const float* b1            = (const float*)d_in[13];
    const float* W2            = (const float*)d_in[14];
    const float* b2            = (const float*)d_in[15];
    const float* rel_w         = (const float*)d_in[16];
    const float* conv_W        = (const float*)d_in[17];
    const float* conv_b        = (const float*)d_in[18];

    char* ws = (char*)d_ws;
    size_t off = 0;
    auto carve = [&](size_t bytes) -> char* {
        char* p = ws + off;
        off = (off + bytes + 255) & ~(size_t)255;
        return p;
    };
    float*    scalars = (float*)carve(256);                 // [0]=thr [1]=THR [3]=pna_mean
    unsigned* state   = (unsigned*)carve(256);              // [0..3]=radix state [8..11]=arrival
    unsigned* countp  = (unsigned*)carve(256);
    float*    qh      = (float*)carve(256);
    unsigned* ghn     = (unsigned*)carve(1024);
    unsigned* ghw     = (unsigned*)carve(1024);
    float*    score   = (float*)carve((size_t)NT * 4);
    float*    sigp    = (float*)carve((size_t)NT * 4);
    float*    hidden  = (float*)carve((size_t)NT * 64 * 4);
    float*    updc    = (float*)carve((size_t)NT * 64 * 4);
    float*    feat    = (float*)carve((size_t)CHUNK * 256 * 4);
    float*    ampatt  = (float*)carve((size_t)CHUNK * 2 * 4);
    int*      list    = (int*)carve((size_t)NT * 4);
    unsigned* degb    = (unsigned*)carve((size_t)N_NODES * 4);
    unsigned* degbt   = (unsigned*)carve((size_t)NT * 4);
    unsigned* rowptr  = (unsigned*)carve((size_t)(N_NODES + 1) * 4);
    unsigned* cursor  = (unsigned*)carve((size_t)N_NODES * 4);
    unsigned* inedge  = (unsigned*)carve((size_t)2 * E_EDGES * 4);
    if (off > ws_size) return;

    hipMemsetAsync(scalars, 0, 256, stream);
    hipMemsetAsync(state, 0, 256, stream);
    hipMemsetAsync(ghn, 0, 1024, stream);
    hipMemsetAsync(ghw, 0, 1024, stream);
    hipMemsetAsync(score, 0, (size_t)NT * 4, stream);
    hipMemsetAsync(degb, 0, (size_t)N_NODES * 4, stream);

    count_deg<<<(E_EDGES + 255) / 256, 256, 0, stream>>>(edge_index, degb);
    scan_degrees<<<1, 1024, 0, stream>>>(degb, rowptr, cursor);
    scatter_edges<<<(E_EDGES + 255) / 256, 256, 0, stream>>>(edge_index, edge_attr, cursor, inedge);
    tile_degb<<<(NT + 255) / 256, 256, 0, stream>>>(degb, degbt);
    pna_kernel<<<1, 1024, 0, stream>>>(degb, scalars);
    init_hidden<<<(NT * 64 + 255) / 256, 256, 0, stream>>>(text, hidden);
    init_heads<<<1, 256, 0, stream>>>(h_index, r_index, hidden_states, rel_table,
                                      W_lin, b_lin, W1, b1, W2, b2, hidden, score, qh);

    for (int l = 0; l < 3; ++l) {
        for (int p = 0; p < 4; ++p)
            select_pass<<<40, 256, 0, stream>>>(score, degbt, ghn, ghw, state,
                                                scalars, countp, p);
        compact_sig<<<(NT + 255) / 256, 256, 0, stream>>>(score, degbt, scalars,
                                                          countp, list, sigp);
        for (int c = 0; c < NCHUNK; ++c) {
            int mbase = c * CHUNK;
            agg_feat<<<CHUNK / 4, 256, 0, stream>>>(sigp, hidden, rowptr, inedge, rel_w,
                                                    scalars, countp, list, feat, ampatt,
                                                    l, mbase);
            gemm_upd<<<CHUNK / 64, 256, 0, stream>>>(conv_W, conv_b, countp, feat, ampatt,
                                                     updc, l, mbase);
        }
        apply_score_gemm<<<(NT + 63) / 64, 256, 0, stream>>>(hidden, updc, score, countp,
                                                             list, W_lin, qh, W1, b1, W2, b2);
    }
    gather_out<<<1, 64, 0, stream>>>(score, t_index, (float*)d_out);
}

// Round 5
// 437.238 us; speedup vs baseline: 4.3545x; 1.2928x over previous
//
#include <hip/hip_runtime.h>
#include <math.h>

#define N_NODES 10000
#define E_EDGES 50000
#define NT      40000
#define KS_N    4000
#define ES_E    40000
#define WTOT    400000u   // sum of in-degrees over batched graph (2*E*B), constant
#define CHUNK   16384     // fallback chunk size when ws is small

// ---------- helpers ----------
__device__ __forceinline__ unsigned f2u(float f) {
    unsigned b = __float_as_uint(f);
    return (b & 0x80000000u) ? ~b : (b | 0x80000000u);
}
__device__ __forceinline__ float u2f(unsigned u) {
    unsigned b = (u & 0x80000000u) ? (u & 0x7fffffffu) : ~u;
    return __uint_as_float(b);
}
__device__ __forceinline__ float wave_sum64(float x) {
    for (int off = 32; off > 0; off >>= 1) x += __shfl_down(x, off, 64);
    return x;  // valid on lane 0
}

// ---------- graph build ----------
__global__ void count_deg(const int* __restrict__ ei, unsigned* __restrict__ deg) {
    int j = blockIdx.x * 256 + threadIdx.x;
    if (j < E_EDGES) {
        atomicAdd(&deg[ei[j]], 1u);
        atomicAdd(&deg[ei[E_EDGES + j]], 1u);
    }
}

__global__ __launch_bounds__(1024) void scan_degrees(const unsigned* __restrict__ deg,
                                                     unsigned* __restrict__ rowptr,
                                                     unsigned* __restrict__ cursor) {
    __shared__ unsigned wsum[16];
    __shared__ unsigned carry;
    int tid = threadIdx.x, lane = tid & 63, w = tid >> 6;
    if (tid == 0) carry = 0;
    __syncthreads();
    for (int base = 0; base < N_NODES; base += 1024) {
        int i = base + tid;
        unsigned v = (i < N_NODES) ? deg[i] : 0u;
        unsigned x = v;
        for (int off = 1; off < 64; off <<= 1) {
            unsigned y = __shfl_up(x, off, 64);
            if (lane >= off) x += y;
        }
        if (lane == 63) wsum[w] = x;
        __syncthreads();
        if (tid < 16) {
            unsigned s = wsum[tid];
            for (int off = 1; off < 16; off <<= 1) {
                unsigned y = __shfl_up(s, off, 64);
                if (tid >= off) s += y;
            }
            wsum[tid] = s;
        }
        __syncthreads();
        unsigned woff = (w > 0) ? wsum[w - 1] : 0u;
        unsigned excl = carry + woff + x - v;
        if (i < N_NODES) { rowptr[i] = excl; cursor[i] = excl; }
        __syncthreads();
        if (tid == 0) carry += wsum[15];
        __syncthreads();
    }
    if (tid == 0) rowptr[N_NODES] = carry;
}

__global__ void scatter_edges(const int* __restrict__ ei, const int* __restrict__ ea,
                              unsigned* __restrict__ cursor, unsigned* __restrict__ inedge) {
    int j = blockIdx.x * 256 + threadIdx.x;
    if (j < E_EDGES) {
        unsigned s = (unsigned)ei[j];
        unsigned d = (unsigned)ei[E_EDGES + j];
        unsigned a = (unsigned)ea[j];
        unsigned p1 = atomicAdd(&cursor[d], 1u);
        inedge[p1] = s | (a << 16);
        unsigned p2 = atomicAdd(&cursor[s], 1u);
        inedge[p2] = d | (a << 16);
    }
}

__global__ void tile_degb(const unsigned* __restrict__ degb, unsigned* __restrict__ degbt) {
    int v = blockIdx.x * 256 + threadIdx.x;
    if (v < NT) degbt[v] = degb[v % N_NODES];
}

// deterministic single-block pna mean
__global__ __launch_bounds__(1024) void pna_kernel(const unsigned* __restrict__ degb,
                                                   float* __restrict__ scalars) {
    __shared__ float ws[16];
    int tid = threadIdx.x;
    float s = 0.0f;
    for (int i = tid; i < N_NODES; i += 1024) s += logf((float)degb[i] + 1.0f);
    for (int off = 32; off > 0; off >>= 1) s += __shfl_down(s, off, 64);
    if ((tid & 63) == 0) ws[tid >> 6] = s;
    __syncthreads();
    if (tid == 0) {
        float t = 0.0f;
        for (int i = 0; i < 16; ++i) t += ws[i];
        scalars[3] = t / (float)N_NODES;
    }
}

// ---------- init ----------
__global__ void init_hidden(const float* __restrict__ text, float* __restrict__ hidden) {
    int i = blockIdx.x * 256 + threadIdx.x;
    if (i < NT * 64) {
        int v = i >> 6;
        hidden[i] = (v < N_NODES) ? text[i] : 0.0f;
    }
}

__device__ float wave_score_g(float hid, float rel, const float* Wlin, const float* blin,
                              const float* W1, const float* b1, const float* W2, float b2v,
                              int lane) {
    float heur = blin[lane];
    for (int i = 0; i < 64; ++i) heur += __shfl(hid, i, 64) * Wlin[i * 64 + lane];
    for (int i = 0; i < 64; ++i) heur += __shfl(rel, i, 64) * Wlin[(64 + i) * 64 + lane];
    float x = hid * heur;
    float a0 = b1[lane], a1 = b1[64 + lane];
    for (int i = 0; i < 64; ++i) {
        float xv = __shfl(x, i, 64);
        a0 += xv * W1[i * 128 + lane];
        a1 += xv * W1[i * 128 + 64 + lane];
    }
    a0 = fmaxf(a0, 0.0f); a1 = fmaxf(a1, 0.0f);
    float part = a0 * W2[lane] + a1 * W2[64 + lane];
    part = wave_sum64(part);
    part = __shfl(part, 0, 64);
    return part + b2v;
}

__global__ void init_heads(const int* __restrict__ h_index, const int* __restrict__ r_index,
                           const float* __restrict__ hidden_states,
                           const float* __restrict__ rel_table,
                           const float* __restrict__ W_lin, const float* __restrict__ b_lin,
                           const float* __restrict__ W1, const float* __restrict__ b1,
                           const float* __restrict__ W2, const float* __restrict__ b2,
                           float* __restrict__ hidden, float* __restrict__ score,
                           float* __restrict__ qh) {
    __shared__ float q0[64];
    int tid = threadIdx.x, w = tid >> 6, lane = tid & 63;
    int b = w;  // 4 waves, one per batch element
    int h0 = h_index[b * 16] + b * N_NODES;
    float hs  = hidden_states[b * 64 + lane];
    float rel = rel_table[r_index[b * 16] * 64 + lane];
    hidden[h0 * 64 + lane] = hs;
    if (b == 0) q0[lane] = rel;
    float s = wave_score_g(hs, rel, W_lin, b_lin, W1, b1, W2, b2[0], lane);
    if (lane == 0) score[h0] = s;
    __syncthreads();
    if (w == 0) {  // qh[t] = sum_i q0[i]*W_lin[64+i][t] + b_lin[t]
        float acc = b_lin[lane];
        for (int i = 0; i < 64; ++i) acc += q0[i] * W_lin[(64 + i) * 64 + lane];
        qh[lane] = acc;
    }
}

// ---------- dual radix select, pick folded in via last-block pattern ----------
__device__ void block_pick(unsigned h, unsigned r, unsigned* outd, unsigned* outr,
                           unsigned* scr) {
    // 256 threads; exactly one digit d satisfies excl<=r<excl+h. scr >= 8 words.
    int tid = threadIdx.x, lane = tid & 63, w = tid >> 6;
    __syncthreads();
    unsigned x = h;
    for (int off = 1; off < 64; off <<= 1) {
        unsigned y = __shfl_up(x, off, 64);
        if (lane >= off) x += y;
    }
    if (lane == 63) scr[w] = x;
    __syncthreads();
    unsigned woff = 0;
    for (int i = 0; i < 4; ++i) if (i < w) woff += scr[i];
    unsigned excl = woff + x - h;
    if (r >= excl && r < excl + h) { scr[4] = (unsigned)tid; scr[5] = r - excl; }
    __syncthreads();
    *outd = scr[4]; *outr = scr[5];
}

__global__ __launch_bounds__(256) void select_pass(
    const float* __restrict__ score, const unsigned* __restrict__ degbt,
    unsigned* __restrict__ ghn, unsigned* __restrict__ ghw,
    unsigned* __restrict__ state, float* __restrict__ scalars,
    unsigned* __restrict__ countp, int pass) {
    __shared__ unsigned lh[512];
    __shared__ unsigned scr[8];
    __shared__ unsigned sh_last;
    int tid = threadIdx.x;
    lh[tid] = 0; lh[256 + tid] = 0;
    __syncthreads();
    unsigned pn = state[0], pw = state[2];
    int shift = 24 - pass * 8;
    for (int v = blockIdx.x * 256 + tid; v < NT; v += gridDim.x * 256) {
        unsigned key = f2u(score[v]);
        unsigned wg = degbt[v];
        unsigned dig = (key >> shift) & 255u;
        if (pass == 0) {
            atomicAdd(&lh[dig], 1u);
            if (wg) atomicAdd(&lh[256 + dig], wg);
        } else {
            unsigned hi = key >> (shift + 8);
            if (hi == pn) atomicAdd(&lh[dig], 1u);
            if (wg && hi == pw) atomicAdd(&lh[256 + dig], wg);
        }
    }
    __syncthreads();
    if (lh[tid]) atomicAdd(&ghn[tid], lh[tid]);
    if (lh[256 + tid]) atomicAdd(&ghw[tid], lh[256 + tid]);
    __threadfence();
    if (tid == 0) sh_last = atomicAdd(&state[8 + pass], 1u);
    __syncthreads();
    if (sh_last != gridDim.x - 1) return;
    // ---- last block: pick digit for both selects, reset hists ----
    unsigned hn = atomicAdd(&ghn[tid], 0u);
    unsigned hw = atomicAdd(&ghw[tid], 0u);
    ghn[tid] = 0; ghw[tid] = 0;
    unsigned rn, rw_;
    if (pass == 0) { pn = 0; rn = NT - KS_N; pw = 0; rw_ = WTOT - ES_E; }
    else { rn = state[1]; rw_ = state[3]; }
    unsigned dn, rn2, dw, rw2;
    block_pick(hn, rn, &dn, &rn2, scr);
    block_pick(hw, rw_, &dw, &rw2, scr);
    if (tid == 0) {
        pn = (pn << 8) | dn;
        pw = (pw << 8) | dw;
        state[0] = pn; state[1] = rn2; state[2] = pw; state[3] = rw2;
        state[8 + pass] = 0;  // reset arrival counter for next layer
        if (pass == 3) {
            float thr = u2f(pn), thre = u2f(pw);
            scalars[0] = thr;
            scalars[1] = fmaxf(thr, thre);  // effective edge/node threshold
            *countp = 0;
        }
    }
}

// ---------- compact + sigmoid precompute ----------
__global__ void compact_sig(const float* __restrict__ score, const unsigned* __restrict__ degbt,
                            const float* __restrict__ scalars, unsigned* __restrict__ countp,
                            int* __restrict__ list, float* __restrict__ sigp) {
    int v = blockIdx.x * 256 + threadIdx.x;
    if (v >= NT) return;
    float sc = score[v];
    bool pass = sc >= scalars[1];
    float sg = -1.0f;
    if (pass) sg = 1.0f / (1.0f + expf(-sc));
    sigp[v] = sg;
    if (pass && degbt[v] > 0) {
        unsigned p = atomicAdd(countp, 1u);
        list[p] = v;
    }
}

// ---------- per-node edge aggregation: one node per wave, no LDS ----------
__global__ __launch_bounds__(256) void agg_feat(
    const float* __restrict__ sigp, const float* __restrict__ hidden,
    const unsigned* __restrict__ rowptr, const unsigned* __restrict__ inedge,
    const float* __restrict__ rel_w, const float* __restrict__ scalars,
    const unsigned* __restrict__ countp, const int* __restrict__ list,
    float* __restrict__ feat, float* __restrict__ ampatt, int layer,
    int mbase, int climit) {
    int count = (int)*countp;
    int cc = count - mbase; if (cc > climit) cc = climit;
    int tid = threadIdx.x, w = tid >> 6, lane = tid & 63;
    int li = blockIdx.x * 4 + w;
    if (li >= cc) return;
    int v = list[mbase + li];
    int b = v / N_NODES;
    int boff = b * N_NODES;
    int n = v - boff;
    const float* rw = rel_w + (size_t)layer * 400 * 64;
    unsigned r0 = rowptr[n], r1 = rowptr[n + 1];
    float sum = 0.f, sq = 0.f, mx = -INFINITY, mn = INFINITY;
    int cnt = 0;
    #pragma unroll 2
    for (unsigned e = r0; e < r1; ++e) {
        unsigned pk = inedge[e];
        int src = (int)(pk & 0xffffu) + boff;
        float sg = sigp[src];
        float h  = hidden[((size_t)src << 6) + lane];
        float rv = rw[((size_t)(pk >> 16) << 6) + lane];
        bool valid = sg >= 0.0f;
        float mval = sg * h * rv;
        if (valid) { sum += mval; sq += mval * mval; }
        mx = fmaxf(mx, valid ? mval : -INFINITY);
        mn = fminf(mn, valid ? mval : INFINITY);
        cnt += valid ? 1 : 0;
    }
    float denom = cnt > 0 ? (float)cnt : 1.0f;
    float mean = sum / denom;
    float sd = sqrtf(fmaxf(sq / denom - mean * mean, 0.0f) + 1e-6f);
    float* fr = feat + ((size_t)li << 8);
    fr[lane]        = mean;
    fr[64 + lane]   = cnt > 0 ? mx : 0.0f;
    fr[128 + lane]  = cnt > 0 ? mn : 0.0f;
    fr[192 + lane]  = sd;
    if (lane == 0) {
        float pna = scalars[3];
        float sl = logf((float)cnt + 1.0f);
        ampatt[li * 2]     = sl / pna;
        ampatt[li * 2 + 1] = pna / (sl + 1e-6f);
    }
}

// ---------- tiled fp32 GEMM: upd[32 x 64] = feat[32 x 256] @ (W0 + amp*W1 + att*W2) ----------
// M=32 rows/block for grid-based occupancy; FMA order per output identical to prior version.
#define FMA4(C, av, bv) { C[0] += av * bv.x; C[1] += av * bv.y; C[2] += av * bv.z; C[3] += av * bv.w; }

__global__ __launch_bounds__(256) void gemm_upd(
    const float* __restrict__ conv_W, const float* __restrict__ conv_b,
    const unsigned* __restrict__ countp, const float* __restrict__ feat,
    const float* __restrict__ ampatt, float* __restrict__ updc,
    int layer, int mbase, int climit) {
    __shared__ float sA[32][34];     // [kk][row], 4.35 KB
    __shared__ float sB[32][196];    // [kk][3*64], 25 KB
    __shared__ float sAmp[32], sAtt[32];
    int count = (int)*countp;
    int cc = count - mbase; if (cc > climit) cc = climit;
    int m0 = blockIdx.x * 32;
    if (m0 >= cc) return;
    int tid = threadIdx.x;
    if (tid < 32) {
        int rl = m0 + tid;
        float a = 0.f, t = 0.f;
        if (rl < cc) { a = ampatt[rl * 2]; t = ampatt[rl * 2 + 1]; }
        sAmp[tid] = a; sAtt[tid] = t;
    }
    int mg = tid >> 4, ng = tid & 15;   // mg 0..15 -> rows mg*2, mg*2+1
    int j0 = ng * 4;
    float c0[2][4] = {}, c1[2][4] = {}, c2[2][4] = {};
    const float* Wl = conv_W + (size_t)layer * 768 * 64;
    const float4* feat4 = (const float4*)feat;
    int arow = tid >> 3, akq = tid & 7;  // A-tile load assignment (1 float4/thread)
    for (int k0 = 0; k0 < 256; k0 += 32) {
        __syncthreads();
        {   // A tile 32 rows x 32 k, stored [k][m]   (m0+31 < climit since both %32==0)
            float4 va = feat4[(((size_t)(m0 + arow)) << 6) + (k0 >> 2) + akq];
            sA[akq * 4 + 0][arow] = va.x; sA[akq * 4 + 1][arow] = va.y;
            sA[akq * 4 + 2][arow] = va.z; sA[akq * 4 + 3][arow] = va.w;
        }
        #pragma unroll
        for (int it = 0; it < 6; ++it) {  // B tile 32 x 192
            int fi = it * 256 + tid;
            int rr = fi >> 4, q = fi & 15;
            int part = rr >> 5, kk = rr & 31;
            float4 vb = *(const float4*)(Wl + (((size_t)(part * 256 + k0 + kk)) << 6) + q * 4);
            float* d = &sB[kk][part * 64 + q * 4];
            d[0] = vb.x; d[1] = vb.y; d[2] = vb.z; d[3] = vb.w;
        }
        __syncthreads();
        #pragma unroll 4
        for (int kk = 0; kk < 32; ++kk) {
            float a0 = sA[kk][mg * 2];
            float a1 = sA[kk][mg * 2 + 1];
            float4 b0 = *(const float4*)&sB[kk][j0];
            float4 b1 = *(const float4*)&sB[kk][64 + j0];
            float4 b2 = *(const float4*)&sB[kk][128 + j0];
            FMA4(c0[0], a0, b0) FMA4(c0[1], a1, b0)
            FMA4(c1[0], a0, b1) FMA4(c1[1], a1, b1)
            FMA4(c2[0], a0, b2) FMA4(c2[1], a1, b2)
        }
    }
    const float4 bias = *(const float4*)(conv_b + layer * 64 + j0);
    #pragma unroll
    for (int mi = 0; mi < 2; ++mi) {
        int ml = mg * 2 + mi;
        int rl = m0 + ml;
        if (rl < cc) {
            float amp = sAmp[ml], att = sAtt[ml];
            float4 o;
            o.x = fmaxf(c0[mi][0] + amp * c1[mi][0] + att * c2[mi][0] + bias.x, 0.0f);
            o.y = fmaxf(c0[mi][1] + amp * c1[mi][1] + att * c2[mi][1] + bias.y, 0.0f);
            o.z = fmaxf(c0[mi][2] + amp * c1[mi][2] + att * c2[mi][2] + bias.z, 0.0f);
            o.w = fmaxf(c0[mi][3] + amp * c1[mi][3] + att * c2[mi][3] + bias.w, 0.0f);
            *(float4*)(updc + (((size_t)(mbase + rl)) << 6) + j0) = o;
        }
    }
}

// ---------- apply update + score MLP as block-tiled GEMM (64 nodes/block) ----------
// Preserves the exact fp32 accumulation order of the wave-serial version.
__global__ __launch_bounds__(256) void apply_score_gemm(
    float* __restrict__ hidden, const float* __restrict__ updc,
    float* __restrict__ score, const unsigned* __restrict__ countp,
    const int* __restrict__ list,
    const float* __restrict__ W_lin, const float* __restrict__ qh,
    const float* __restrict__ W1, const float* __restrict__ b1,
    const float* __restrict__ W2, const float* __restrict__ b2) {
    __shared__ float sH[64][65];   // h tile; reused as p tile in phase 3
    __shared__ float sX[64][65];   // x = h * heur
    int count = (int)*countp;
    int m0 = blockIdx.x * 64;
    if (m0 >= count) return;
    int tid = threadIdx.x;

    // ---- phase 0: load h, add upd, store back, stage in LDS ----
    {
        int q = tid & 15;
        int mB = tid >> 4;
        #pragma unroll
        for (int r = 0; r < 4; ++r) {
            int m = r * 16 + mB;
            int idx = m0 + m;
            float4 hv = {0.f, 0.f, 0.f, 0.f};
            if (idx < count) {
                int v = list[idx];
                hv = *(const float4*)&hidden[((size_t)v << 6) + q * 4];
                float4 uv = *(const float4*)&updc[((size_t)idx << 6) + q * 4];
                hv.x += uv.x; hv.y += uv.y; hv.z += uv.z; hv.w += uv.w;
                *(float4*)&hidden[((size_t)v << 6) + q * 4] = hv;
            }
            sH[m][q * 4 + 0] = hv.x; sH[m][q * 4 + 1] = hv.y;
            sH[m][q * 4 + 2] = hv.z; sH[m][q * 4 + 3] = hv.w;
        }
    }
    __syncthreads();

    int mg = tid >> 4, ng = tid & 15;
    const float4* Wl4 = (const float4*)W_lin;
    const float4* W14 = (const float4*)W1;
    const float4* qh4 = (const float4*)qh;
    const float4* b14 = (const float4*)b1;
    const float4* W24 = (const float4*)W2;

    // ---- phase 1: heur = H @ Wl + qh ; x = h * heur ----
    {
        float4 qv = qh4[ng];
        float acc[4][4];
        #pragma unroll
        for (int mi = 0; mi < 4; ++mi) {
            acc[mi][0] = qv.x; acc[mi][1] = qv.y; acc[mi][2] = qv.z; acc[mi][3] = qv.w;
        }
        for (int k = 0; k < 64; ++k) {
            float4 bv = Wl4[k * 16 + ng];
            #pragma unroll
            for (int mi = 0; mi < 4; ++mi) {
                float av = sH[mg * 4 + mi][k];
                acc[mi][0] += av * bv.x; acc[mi][1] += av * bv.y;
                acc[mi][2] += av * bv.z; acc[mi][3] += av * bv.w;
            }
        }
        #pragma unroll
        for (int mi = 0; mi < 4; ++mi) {
            int m = mg * 4 + mi;
            #pragma unroll
            for (int ni = 0; ni < 4; ++ni)
                sX[m][ng * 4 + ni] = sH[m][ng * 4 + ni] * acc[mi][ni];
        }
    }
    __syncthreads();

    // ---- phase 2: a = relu(X @ W1 + b1); p = aLo*W2lo + aHi*W2hi ----
    {
        float4 bA = b14[ng], bB = b14[16 + ng];
        float accA[4][4], accB[4][4];
        #pragma unroll
        for (int mi = 0; mi < 4; ++mi) {
            accA[mi][0] = bA.x; accA[mi][1] = bA.y; accA[mi][2] = bA.z; accA[mi][3] = bA.w;
            accB[mi][0] = bB.x; accB[mi][1] = bB.y; accB[mi][2] = bB.z; accB[mi][3] = bB.w;
        }
        for (int k = 0; k < 64; ++k) {
            float4 bvA = W14[k * 32 + ng];
            float4 bvB = W14[k * 32 + 16 + ng];
            #pragma unroll
            for (int mi = 0; mi < 4; ++mi) {
                float av = sX[mg * 4 + mi][k];
                accA[mi][0] += av * bvA.x; accA[mi][1] += av * bvA.y;
                accA[mi][2] += av * bvA.z; accA[mi][3] += av * bvA.w;
                accB[mi][0] += av * bvB.x; accB[mi][1] += av * bvB.y;
                accB[mi][2] += av * bvB.z; accB[mi][3] += av * bvB.w;
            }
        }
        float4 w2A = W24[ng], w2B = W24[16 + ng];
        #pragma unroll
        for (int mi = 0; mi < 4; ++mi) {
            int m = mg * 4 + mi;
            float pA0 = fmaxf(accA[mi][0], 0.f), pB0 = fmaxf(accB[mi][0], 0.f);
            float pA1 = fmaxf(accA[mi][1], 0.f), pB1 = fmaxf(accB[mi][1], 0.f);
            float pA2 = fmaxf(accA[mi][2], 0.f), pB2 = fmaxf(accB[mi][2], 0.f);
            float pA3 = fmaxf(accA[mi][3], 0.f), pB3 = fmaxf(accB[mi][3], 0.f);
            sH[m][ng * 4 + 0] = pA0 * w2A.x + pB0 * w2B.x;
            sH[m][ng * 4 + 1] = pA1 * w2A.y + pB1 * w2B.y;
            sH[m][ng * 4 + 2] = pA2 * w2A.z + pB2 * w2B.z;
            sH[m][ng * 4 + 3] = pA3 * w2A.w + pB3 * w2B.w;
        }
    }
    __syncthreads();

    // ---- phase 3: exact shfl_down tree per row, write score ----
    {
        float b2v = b2[0];
        int w = tid >> 6, lane = tid & 63;
        #pragma unroll 4
        for (int t = 0; t < 16; ++t) {
            int m = w * 16 + t;
            float p = sH[m][lane];
            float s = wave_sum64(p);
            if (lane == 0) {
                int idx = m0 + m;
                if (idx < count) score[list[idx]] = s + b2v;
            }
        }
    }
}

// ---------- output gather ----------
__global__ void gather_out(const float* __restrict__ score, const int* __restrict__ t_index,
                           float* __restrict__ out) {
    int i = threadIdx.x;  // 64 threads
    int b = i >> 4;
    out[i] = score[t_index[i] + b * N_NODES];
}

// ---------- launcher ----------
extern "C" void kernel_launch(void* const* d_in, const int* in_sizes, int n_in,
                              void* d_out, int out_size, void* d_ws, size_t ws_size,
                              hipStream_t stream) {
    const int*   h_index       = (const int*)d_in[0];
    const int*   r_index       = (const int*)d_in[1];
    const int*   t_index       = (const int*)d_in[2];
    const float* hidden_states = (const float*)d_in[3];
    const int*   edge_index    = (const int*)d_in[5];
    const int*   edge_attr     = (const int*)d_in[6];
    const float* text          = (const float*)d_in[7];
    const float* rel_table     = (const float*)d_in[9];
    const float* W_lin         = (const float*)d_in[10];
    const float* b_lin         = (const float*)d_in[11];
    const float* W1            = (const float*)d_in[12];
    const float* b1            = (const float*)d_in[13];
    const float* W2            = (const float*)d_in[14];
    const float* b2            = (const float*)d_in[15];
    const float* rel_w         = (const float*)d_in[16];
    const float* conv_W        = (const float*)d_in[17];
    const float* conv_b        = (const float*)d_in[18];

    // choose full (unchunked) path if scratch allows
    auto layout_bytes = [](size_t fch) -> size_t {
        auto al = [](size_t x) { return (x + 255) & ~(size_t)255; };
        size_t o = 0;
        o += al(256) * 3;                      // scalars, state, countp
        o += al(1024) * 2;                     // ghn, ghw
        o += al((size_t)NT * 4);               // score
        o += al((size_t)N_NODES * 4);          // degb
        o += al(256);                          // qh
        o += al((size_t)NT * 4);               // sigp
        o += al((size_t)NT * 64 * 4);          // hidden
        o += al((size_t)NT * 64 * 4);          // updc
        o += al(fch * 256 * 4);                // feat
        o += al(fch * 2 * 4);                  // ampatt
        o += al((size_t)NT * 4);               // list
        o += al((size_t)NT * 4);               // degbt
        o += al((size_t)(N_NODES + 1) * 4);    // rowptr
        o += al((size_t)N_NODES * 4);          // cursor
        o += al((size_t)2 * E_EDGES * 4);      // inedge
        return o;
    };
    const size_t FCH = (layout_bytes(NT) <= ws_size) ? (size_t)NT : (size_t)CHUNK;
    const int NCH = (FCH == (size_t)NT) ? 1 : 3;

    char* ws = (char*)d_ws;
    size_t off = 0;
    auto carve = [&](size_t bytes) -> char* {
        char* p = ws + off;
        off = (off + bytes + 255) & ~(size_t)255;
        return p;
    };
    // ---- zero-initialized group (contiguous; single memset) ----
    float*    scalars = (float*)carve(256);                 // [0]=thr [1]=THR [3]=pna_mean
    unsigned* state   = (unsigned*)carve(256);              // [0..3]=radix state [8..11]=arrival
    unsigned* countp  = (unsigned*)carve(256);
    unsigned* ghn     = (unsigned*)carve(1024);
    unsigned* ghw     = (unsigned*)carve(1024);
    float*    score   = (float*)carve((size_t)NT * 4);
    unsigned* degb    = (unsigned*)carve((size_t)N_NODES * 4);
    size_t zero_end = off;
    // ---- rest ----
    float*    qh      = (float*)carve(256);
    float*    sigp    = (float*)carve((size_t)NT * 4);
    float*    hidden  = (float*)carve((size_t)NT * 64 * 4);
    float*    updc    = (float*)carve((size_t)NT * 64 * 4);
    float*    feat    = (float*)carve(FCH * 256 * 4);
    float*    ampatt  = (float*)carve(FCH * 2 * 4);
    int*      list    = (int*)carve((size_t)NT * 4);
    unsigned* degbt   = (unsigned*)carve((size_t)NT * 4);
    unsigned* rowptr  = (unsigned*)carve((size_t)(N_NODES + 1) * 4);
    unsigned* cursor  = (unsigned*)carve((size_t)N_NODES * 4);
    unsigned* inedge  = (unsigned*)carve((size_t)2 * E_EDGES * 4);
    if (off > ws_size) return;

    hipMemsetAsync(ws, 0, zero_end, stream);

    count_deg<<<(E_EDGES + 255) / 256, 256, 0, stream>>>(edge_index, degb);
    scan_degrees<<<1, 1024, 0, stream>>>(degb, rowptr, cursor);
    scatter_edges<<<(E_EDGES + 255) / 256, 256, 0, stream>>>(edge_index, edge_attr, cursor, inedge);
    tile_degb<<<(NT + 255) / 256, 256, 0, stream>>>(degb, degbt);
    pna_kernel<<<1, 1024, 0, stream>>>(degb, scalars);
    init_hidden<<<(NT * 64 + 255) / 256, 256, 0, stream>>>(text, hidden);
    init_heads<<<1, 256, 0, stream>>>(h_index, r_index, hidden_states, rel_table,
                                      W_lin, b_lin, W1, b1, W2, b2, hidden, score, qh);

    const int climit  = (int)FCH;
    const int aggGrid = climit / 4;
    const int gemGrid = climit / 32;
    for (int l = 0; l < 3; ++l) {
        for (int p = 0; p < 4; ++p)
            select_pass<<<40, 256, 0, stream>>>(score, degbt, ghn, ghw, state,
                                                scalars, countp, p);
        compact_sig<<<(NT + 255) / 256, 256, 0, stream>>>(score, degbt, scalars,
                                                          countp, list, sigp);
        for (int c = 0; c < NCH; ++c) {
            int mbase = c * climit;
            agg_feat<<<aggGrid, 256, 0, stream>>>(sigp, hidden, rowptr, inedge, rel_w,
                                                  scalars, countp, list, feat, ampatt,
                                                  l, mbase, climit);
            gemm_upd<<<gemGrid, 256, 0, stream>>>(conv_W, conv_b, countp, feat, ampatt,
                                                  updc, l, mbase, climit);
        }
        apply_score_gemm<<<(NT + 63) / 64, 256, 0, stream>>>(hidden, updc, score, countp,
                                                             list, W_lin, qh, W1, b1, W2, b2);
    }
    gather_out<<<1, 64, 0, stream>>>(score, t_index, (float*)d_out);
}